// Round 12
// baseline (364.503 us; speedup 1.0000x reference)
//
#include <hip/hip_runtime.h>

#define SEQ    2048
#define DM     2048
#define QKVN   3072
#define VTR    64

typedef short s16x8 __attribute__((ext_vector_type(8)));
typedef float f32x4 __attribute__((ext_vector_type(4)));
typedef unsigned short us;

#define MFMA(a,b,c) __builtin_amdgcn_mfma_f32_16x16x32_bf16((a),(b),(c),0,0,0)

__device__ __forceinline__ float bf2f(us u) {
    unsigned v = ((unsigned)u) << 16;
    return __builtin_bit_cast(float, v);
}
__device__ __forceinline__ us f2bf(float f) {
    unsigned u = __builtin_bit_cast(unsigned, f);
    u += 0x7FFFu + ((u >> 16) & 1u);
    return (us)(u >> 16);
}
// truncating bf16 store (folds to ds_write_b16_d16_hi) — R5-proven
__device__ __forceinline__ void stp(us* p, float f) {
    *p = (us)(__builtin_bit_cast(unsigned, f) >> 16);
}
__device__ __forceinline__ void glds16(const us* g, us* l) {
    __builtin_amdgcn_global_load_lds((__attribute__((address_space(1))) void*)g,
                                     (__attribute__((address_space(3))) void*)l, 16, 0, 0);
}

// ---------------------------------------------------------------------------
// Fused input/weight bf16 conversion. x -> xb (float4 idx 0..2097151);
// weights -> wqkvb..wob (contiguous 20 MiB region starting at wqkvb).
// ---------------------------------------------------------------------------
__global__ __launch_bounds__(256) void cvt_all(const float* __restrict__ x,
                                               const float* __restrict__ wq,
                                               const float* __restrict__ wk,
                                               const float* __restrict__ wv,
                                               const float* __restrict__ wo,
                                               us* __restrict__ xb,
                                               us* __restrict__ wdst) {
    int i = blockIdx.x * blockDim.x + threadIdx.x;   // total 4718592 float4s
    const float* src;
    int off;
    if (i < 2097152)      { src = x;  off = 0; }
    else {
        int j = i - 2097152;
        if (j < 1048576)      { src = wq; off = 2097152; }
        else if (j < 1310720) { src = wk; off = 2097152 + 1048576; }
        else if (j < 1572864) { src = wv; off = 2097152 + 1310720; }
        else                  { src = wo; off = 2097152 + 1572864; }
    }
    float4 v = ((const float4*)src)[i - off];
    ushort4 o;
    o.x = f2bf(v.x); o.y = f2bf(v.y); o.z = f2bf(v.z); o.w = f2bf(v.w);
    ((ushort4*)(i < 2097152 ? xb : wdst))[i < 2097152 ? i : i - 2097152] = o;
}

// ---------------------------------------------------------------------------
// R14-validated GEMM (used for gemm1): 128x128 tile, BK=32, 2-phase LDS
// double-buffer, global_load_lds width-16 staging. Grid (32,24) = 768
// blocks -> 3 blocks/CU resident, 100% fill + backfill. R16 calibration:
// per-CU rate of this structure == the 4-phase 256^2 port (~530 TF), so
// fill decides — this config beat the 192-block 256^2 (≈100 vs ≈115 us).
// ROPE=true: inline-trig rotary on cols<2560 (R12 table-lookup regressed).
// ---------------------------------------------------------------------------
template <typename OutT, bool ROPE>
__global__ __launch_bounds__(256) void gemm_bt(const us* __restrict__ A, const us* __restrict__ W,
                                               OutT* __restrict__ C, int M, int N, int K) {
    __shared__ us la[2][128 * 32];
    __shared__ us lb[2][128 * 32];
    const int tid = threadIdx.x, lane = tid & 63, wave = tid >> 6;
    const int quad = lane >> 4, lr = lane & 15;
    const int m0 = blockIdx.x * 128, n0 = blockIdx.y * 128;
    const int wm = (wave & 1) * 64, wn = (wave >> 1) * 64;

    f32x4 acc[4][4] = {};

    const int r0 = wave * 32 + (lane >> 2);
    const int c0 = (lane & 3) * 8;
    const us* ga0 = A + (size_t)(m0 + r0) * K + c0;
    const us* ga1 = A + (size_t)(m0 + r0 + 16) * K + c0;
    const us* gb0 = W + (size_t)(n0 + r0) * K + c0;
    const us* gb1 = W + (size_t)(n0 + r0 + 16) * K + c0;
    const int soff = (wave * 32) * 32;        // wave-uniform staging base (elems)

    auto stage = [&](int kt, int pb) {
        const int k0 = kt * 32;
        glds16(ga0 + k0, &la[pb][soff]);
        glds16(ga1 + k0, &la[pb][soff + 16 * 32]);
        glds16(gb0 + k0, &lb[pb][soff]);
        glds16(gb1 + k0, &lb[pb][soff + 16 * 32]);
    };

    const int NT = K / 32;
    stage(0, 0);
    __syncthreads();                          // drain stage 0
    int cur = 0;
    for (int kt = 0; kt < NT; ++kt) {
        if (kt + 1 < NT) stage(kt + 1, cur ^ 1);   // prefetch next tile (other buf)
        s16x8 af[4], bfr[4];
#pragma unroll
        for (int i = 0; i < 4; i++)
            af[i] = *(const s16x8*)&la[cur][(wm + i * 16 + lr) * 32 + quad * 8];
#pragma unroll
        for (int j = 0; j < 4; j++)
            bfr[j] = *(const s16x8*)&lb[cur][(wn + j * 16 + lr) * 32 + quad * 8];
#pragma unroll
        for (int i = 0; i < 4; i++)
#pragma unroll
            for (int j = 0; j < 4; j++)
                acc[i][j] = MFMA(af[i], bfr[j], acc[i][j]);
        __syncthreads();                      // stage(kt+1) complete; reads done
        cur ^= 1;
    }

#pragma unroll
    for (int i = 0; i < 4; i++)
#pragma unroll
        for (int j = 0; j < 4; j++)
#pragma unroll
            for (int r = 0; r < 4; r++) {
                int row = m0 + wm + i * 16 + quad * 4 + r;
                int col = n0 + wn + j * 16 + lr;
                float v = acc[i][j][r];
                if (ROPE && n0 < 2560) {
                    int pair = (col >> 1) & 31;
                    float inv = exp2f((float)pair * (-13.2877124f / 32.0f));
                    float ang = (float)(row & (SEQ - 1)) * inv;
                    float c = __cosf(ang), sn = __sinf(ang);
                    float p = __shfl_xor(v, 1);
                    v = v * c + ((col & 1) ? p * sn : -p * sn);
                }
                if constexpr (sizeof(OutT) == 2)
                    C[(size_t)row * N + col] = f2bf(v);
                else
                    C[(size_t)row * N + col] = v;
            }
}

// ---------------------------------------------------------------------------
// R16-validated GEMM (used for gemm2): 256x128 tile, BK=64, 512 threads
// (8 waves 2Mx4N), 4 phases-family schedule (2 phases/K-tile), counted
// vmcnt (never 0 mid-loop), raw s_barrier, both-sides swizzle, T5 setprio.
// Grid (16,16) = 256 blocks = 100% CU fill. 537 TF measured.
// Requires: M%256==0, N%128==0, K%64==0, K/64 >= 3.
// ---------------------------------------------------------------------------
template <typename OutT>
__global__ __launch_bounds__(512) void gemm_bt2n(const us* __restrict__ A, const us* __restrict__ W,
                                                 OutT* __restrict__ C, int M, int N, int K) {
    __shared__ us lA[2][2][128 * 64];         // 64 KiB
    __shared__ us lB[2][128 * 64];            // 32 KiB
    const int tid = threadIdx.x, lane = tid & 63, wave = tid >> 6;
    const int quad = lane >> 4, lr = lane & 15;
    const int mh = wave >> 2;                 // wave's A half (128-row group)
    const int wnx = wave & 3;                 // wave's 32-col group
    const int m0 = blockIdx.x * 256, n0 = blockIdx.y * 128;

    const int srow = tid >> 3;
    const int scol = ((tid & 7) ^ (srow & 7)) * 8;
    const int sdst = srow * 64 + (tid & 7) * 8;

    const us* gA = A + (size_t)m0 * K;
    const us* gB = W + (size_t)n0 * K;

    // ty: 0=A0, 1=A1, 2=B
    auto stageH = [&](int t, int ty) {
        const int par = t & 1;
        const us* src;
        us* dst;
        if (ty < 2) { src = gA + (size_t)(ty * 128) * K; dst = &lA[par][ty][0]; }
        else        { src = gB;                           dst = &lB[par][0]; }
        src += t * 64;
        glds16(src + (size_t)srow * K + scol,        dst + sdst);
        glds16(src + (size_t)(srow + 64) * K + scol, dst + sdst + 64 * 64);
    };

    const int rsw = (lr & 7) << 3;
    auto rdA = [&](int par, int kk, int i) {
        return *(const s16x8*)&lA[par][mh][(i * 16 + lr) * 64 + ((kk * 32 + quad * 8) ^ rsw)];
    };
    auto rdB = [&](int par, int kk, int j) {
        return *(const s16x8*)&lB[par][(wnx * 32 + j * 16 + lr) * 64 + ((kk * 32 + quad * 8) ^ rsw)];
    };

    f32x4 acc[8][2] = {};
    const int NT = K / 64;

    // prologue: tile0 {A0,A1,B} + tile1 A0 -> wait all but newest half
    stageH(0, 0); stageH(0, 1); stageH(0, 2); stageH(1, 0);
    asm volatile("s_waitcnt vmcnt(2)" ::: "memory");
    __builtin_amdgcn_s_barrier();

    s16x8 af[2][4], ag[2][4], bfr[2][2];
    for (int t = 0; t < NT; ++t) {
        const int par = t & 1;
        // ---- phase 0: (i 0-3) x (j 0-1) ----
#pragma unroll
        for (int kk = 0; kk < 2; kk++) {
#pragma unroll
            for (int i = 0; i < 4; i++) af[kk][i] = rdA(par, kk, i);
#pragma unroll
            for (int j = 0; j < 2; j++) bfr[kk][j] = rdB(par, kk, j);
        }
        if (t + 1 < NT) stageH(t + 1, 1);
        __builtin_amdgcn_s_barrier();
        asm volatile("s_waitcnt lgkmcnt(0)" ::: "memory");
        __builtin_amdgcn_s_setprio(1);
#pragma unroll
        for (int i = 0; i < 4; i++)
#pragma unroll
            for (int j = 0; j < 2; j++)
#pragma unroll
                for (int kk = 0; kk < 2; kk++)
                    acc[i][j] = MFMA(af[kk][i], bfr[kk][j], acc[i][j]);
        __builtin_amdgcn_s_setprio(0);
        __builtin_amdgcn_s_barrier();
        // ---- phase 1: (i 4-7) x (j 0-1); then stage t+2.A0 (parity par, safe) ----
#pragma unroll
        for (int kk = 0; kk < 2; kk++)
#pragma unroll
            for (int i = 0; i < 4; i++) ag[kk][i] = rdA(par, kk, 4 + i);
        if (t + 1 < NT) stageH(t + 1, 2);
        __builtin_amdgcn_s_barrier();
        asm volatile("s_waitcnt lgkmcnt(0)" ::: "memory");
        __builtin_amdgcn_s_setprio(1);
#pragma unroll
        for (int i = 0; i < 4; i++)
#pragma unroll
            for (int j = 0; j < 2; j++)
#pragma unroll
                for (int kk = 0; kk < 2; kk++)
                    acc[4 + i][j] = MFMA(ag[kk][i], bfr[kk][j], acc[4 + i][j]);
        __builtin_amdgcn_s_setprio(0);
        if (t + 2 < NT) stageH(t + 2, 0);
        if (t + 1 < NT) {
            if (t + 2 < NT) asm volatile("s_waitcnt vmcnt(2)" ::: "memory");
            else            asm volatile("s_waitcnt vmcnt(0)" ::: "memory");
            __builtin_amdgcn_s_barrier();
        }
    }

#pragma unroll
    for (int i = 0; i < 8; i++)
#pragma unroll
        for (int j = 0; j < 2; j++)
#pragma unroll
            for (int r = 0; r < 4; r++) {
                int row = m0 + mh * 128 + i * 16 + quad * 4 + r;
                int col = n0 + wnx * 32 + j * 16 + lr;
                if constexpr (sizeof(OutT) == 2)
                    C[(size_t)row * N + col] = f2bf(acc[i][j][r]);
                else
                    C[(size_t)row * N + col] = acc[i][j][r];
            }
}

// ---------------------------------------------------------------------------
// V transpose from fused qkv buffer (V at col 2560) -> vt (b,kvh, 64, S)
// ---------------------------------------------------------------------------
__global__ __launch_bounds__(256) void transpose_v(const us* __restrict__ qkv, us* __restrict__ vt) {
    __shared__ us tile[64][72];
    const int s0 = blockIdx.x * 64;
    const int bk = blockIdx.y;
    const int b = bk >> 3, kvh = bk & 7;
    const int t = threadIdx.x;
    const int r = t >> 3, cg = (t & 7) * 8;
#pragma unroll
    for (int p = 0; p < 2; p++) {
        int rr = r + p * 32;
        *(s16x8*)&tile[rr][cg] =
            *(const s16x8*)(qkv + (size_t)(b * SEQ + s0 + rr) * QKVN + 2560 + kvh * 64 + cg);
    }
    __syncthreads();
#pragma unroll
    for (int p = 0; p < 2; p++) {
        int d = r + p * 32;
        s16x8 val;
#pragma unroll
        for (int u = 0; u < 8; u++) val[u] = tile[cg + u][d];
        *(s16x8*)(vt + ((size_t)bk * VTR + d) * SEQ + s0 + cg) = val;
    }
}

// ---------------------------------------------------------------------------
// Causal flash attention — R6 4-tile structure + V phase-shift (proven
// neutral, kept). Occupancy RF-pinned at 2 waves/SIMD (unified VGPR+AGPR
// cap 256/wave; this kernel ~200). kf prefetch after last QK use; vf(kb+1)
// at loop bottom after PV. Both K/V global-latency hypotheses measured null
// -> remaining idle is structural; fixing it = swapped-QK rewrite (future).
// P-store scheme = R5-proven scalar stp + lgkmcnt(0). l via ones-col MFMA.
// NOTE R16 anomaly: flash read 135us (vs stable 122.6-123.9 in all prior
// rounds, same code); dur x MfmaUtil invariant -> same MFMA work, more
// stall -> environmental (DVFS/chip-state), re-measure this round.
// ---------------------------------------------------------------------------
__global__ __launch_bounds__(256, 2) void flash_attn(const us* __restrict__ qkv,
                                                     const us* __restrict__ vt,
                                                     us* __restrict__ o) {
    __shared__ us P[4][4][16 * 72];           // [wave][tile]
    const int bh = blockIdx.y, b = bh >> 5, h = bh & 31, kvh = h >> 2;
    const int wave = threadIdx.x >> 6, lane = threadIdx.x & 63;
    const int quad = lane >> 4, lr = lane & 15;
    const int p = ((int)blockIdx.x + (int)(blockIdx.y >> 3)) & 7;
    const int qts[4] = {p, 15 - p, 16 + p, 31 - p};
    const us* kbase = qkv + (size_t)b * SEQ * QKVN + 2048 + kvh * 64;
    const us* vb = vt + (size_t)(b * 8 + kvh) * VTR * SEQ;
    const float QS = 0.125f * 1.44269504f;    // scale * log2(e)

    s16x8 onesb;
    const short ov = (lr == 0) ? (short)0x3F80 : (short)0;
#pragma unroll
    for (int j = 0; j < 8; j++) onesb[j] = ov;

    int q0[4];
    s16x8 qa[4][2];
#pragma unroll
    for (int t = 0; t < 4; t++) {
        q0[t] = qts[t] * 64 + wave * 16;
        const us* qb = qkv + (size_t)(b * SEQ + q0[t]) * QKVN + h * 64;
        qa[t][0] = *(const s16x8*)(qb + (size_t)lr * QKVN + quad * 8);
        qa[t][1] = *(const s16x8*)(qb + (size_t)lr * QKVN + 32 + quad * 8);
#pragma unroll
        for (int j = 0; j < 8; j++) {
            qa[t][0][j] = (short)f2bf(bf2f((us)qa[t][0][j]) * QS);
            qa[t][1][j] = (short)f2bf(bf2f((us)qa[t][1][j]) * QS);
        }
    }

    f32x4 oacc[4][5] = {};                    // per tile: [0..3]=O, [4] col0 = l
    s16x8 kf[8], vf[8];
    {
        const us* kp = kbase + (size_t)lr * QKVN;
#pragma unroll
        for (int nb = 0; nb < 4; nb++) {
            kf[2 * nb]     = *(const s16x8*)(kp + (size_t)nb * 16 * QKVN + quad * 8);
            kf[2 * nb + 1] = *(const s16x8*)(kp + (size_t)nb * 16 * QKVN + 32 + quad * 8);
        }
#pragma unroll
        for (int n = 0; n < 4; n++)
#pragma unroll
            for (int kc = 0; kc < 2; kc++)
                vf[n * 2 + kc] = *(const s16x8*)(vb + (size_t)(n * 16 + lr) * SEQ +
                                                 kc * 32 + quad * 8);
    }

    // QK for one tile -> sc; exp2 -> P[wave][t] (scalar b16 stores, R5-proven)
    auto qk_tile = [&](int t, f32x4* sc) {
#pragma unroll
        for (int nb = 0; nb < 4; nb++) {
            sc[nb] = f32x4{0.f, 0.f, 0.f, 0.f};
            sc[nb] = MFMA(qa[t][0], kf[2 * nb], sc[nb]);
            sc[nb] = MFMA(qa[t][1], kf[2 * nb + 1], sc[nb]);
        }
    };
    auto store_tile = [&](int t, const f32x4* sc, int kb) {
        us* Pt = &P[wave][t][0];
        if (kb == qts[t]) {                   // diagonal block: causal mask
#pragma unroll
            for (int nb = 0; nb < 4; nb++)
#pragma unroll
                for (int r = 0; r < 4; r++) {
                    int key = kb * 64 + nb * 16 + lr, row = q0[t] + quad * 4 + r;
                    float s = (key > row) ? -1e30f : sc[nb][r];
                    stp(&Pt[(quad * 4 + r) * 72 + nb * 16 + lr], exp2f(s));
                }
        } else {
#pragma unroll
            for (int nb = 0; nb < 4; nb++)
#pragma unroll
                for (int r = 0; r < 4; r++)
                    stp(&Pt[(quad * 4 + r) * 72 + nb * 16 + lr], exp2f(sc[nb][r]));
        }
    };

    const int kbmax = qts[3];
    for (int kb = 0; kb <= kbmax; kb++) {
        const bool a0 = (kb <= qts[0]), a1 = (kb <= qts[1]), a2 = (kb <= qts[2]);
        f32x4 sa[4], sb[4];
        // ---- QK pair 1 (tiles 0,1) with current kf ----
        if (a0) qk_tile(0, sa);
        if (a1) qk_tile(1, sb);
        if (a0) store_tile(0, sa, kb);
        if (a1) store_tile(1, sb, kb);
        // ---- QK pair 2 (tiles 2,3) still with current kf ----
        if (a2) qk_tile(2, sa);
        qk_tile(3, sb);                       // tile 3 always active
        // ---- kf prefetch for kb+1 (kf now dead until next iteration) ----
        if (kb < kbmax) {
            const us* kp = kbase + (size_t)((kb + 1) * 64 + lr) * QKVN;
#pragma unroll
            for (int nb = 0; nb < 4; nb++) {
                kf[2 * nb]     = *(const s16x8*)(kp + (size_t)nb * 16 * QKVN + quad * 8);
                kf[2 * nb + 1] = *(const s16x8*)(kp + (size_t)nb * 16 * QKVN + 32 + quad * 8);
            }
        }
        if (a2) store_tile(2, sa, kb);
        store_tile(3, sb, kb);
        asm volatile("s_waitcnt lgkmcnt(0)" ::: "memory");   // wave-private tiles
        // ---- PV for all active tiles, shared vf (loaded one iter ahead) ----
        __builtin_amdgcn_s_setprio(1);
#pragma unroll
        for (int t = 0; t < 4; t++) {
            if (kb <= qts[t]) {
#pragma unroll
                for (int kc = 0; kc < 2; kc++) {
                    s16x8 pa = *(const s16x8*)&P[wave][t][lr * 72 + kc * 32 + quad * 8];
#pragma unroll
                    for (int n = 0; n < 4; n++)
                        oacc[t][n] = MFMA(pa, vf[n * 2 + kc], oacc[t][n]);
                    oacc[t][4] = MFMA(pa, onesb, oacc[t][4]);
                }
            }
        }
        __builtin_amdgcn_s_setprio(0);
        // ---- vf load for kb+1 (vf dead after PV; full next-QK-phase cover) ----
        if (kb < kbmax) {
#pragma unroll
            for (int n = 0; n < 4; n++)
#pragma unroll
                for (int kc = 0; kc < 2; kc++)
                    vf[n * 2 + kc] = *(const s16x8*)(vb + (size_t)(n * 16 + lr) * SEQ +
                                                     (kb + 1) * 64 + kc * 32 + quad * 8);
        }
    }

#pragma unroll
    for (int t = 0; t < 4; t++)
#pragma unroll
        for (int r = 0; r < 4; r++) {
            float l = __shfl(oacc[t][4][r], lane & 48);
            float li = 1.0f / l;
#pragma unroll
            for (int n = 0; n < 4; n++)
                o[(size_t)(b * SEQ + q0[t] + quad * 4 + r) * DM + h * 64 + n * 16 + lr] =
                    f2bf(oacc[t][n][r] * li);
        }
}

// ---------------------------------------------------------------------------
extern "C" void kernel_launch(void* const* d_in, const int* in_sizes, int n_in,
                              void* d_out, int out_size, void* d_ws, size_t ws_size,
                              hipStream_t stream) {
    const float* x  = (const float*)d_in[0];
    const float* wq = (const float*)d_in[1];
    const float* wk = (const float*)d_in[2];
    const float* wv = (const float*)d_in[3];
    const float* wo = (const float*)d_in[4];
    float* out = (float*)d_out;

    char* ws = (char*)d_ws;
    const size_t MB = 1024 * 1024;
    us* xb     = (us*)(ws + 0 * MB);    // 16 MiB; reused as abuf (flash out)
    us* abuf   = (us*)(ws + 0 * MB);
    us* wqkvb  = (us*)(ws + 16 * MB);   // 12 MiB (wq|wk|wv) — contiguous with wob
    us* wob    = (us*)(ws + 28 * MB);   // 8 MiB
    us* qkvbuf = (us*)(ws + 36 * MB);   // 24 MiB (4096 x 3072)
    us* vtbuf  = (us*)(ws + 60 * MB);   // 4 MiB

    dim3 blk(256);
    cvt_all<<<dim3(18432), blk, 0, stream>>>(x, wq, wk, wv, wo, xb, wqkvb);

    gemm_bt<us, true><<<dim3(32, 24), blk, 0, stream>>>(xb, wqkvb, qkvbuf, 4096, 3072, 2048);
    transpose_v<<<dim3(32, 16), blk, 0, stream>>>(qkvbuf, vtbuf);
    flash_attn<<<dim3(8, 64), blk, 0, stream>>>(qkvbuf, vtbuf, abuf);
    gemm_bt2n<float><<<dim3(16, 16), dim3(512), 0, stream>>>(abuf, wob, out, 4096, 2048, 2048);
}

// Round 13
// 341.724 us; speedup vs baseline: 1.0667x; 1.0667x over previous
//
#include <hip/hip_runtime.h>

#define SEQ    2048
#define DM     2048
#define QKVN   3072
#define VTR    64

typedef short s16x8 __attribute__((ext_vector_type(8)));
typedef float f32x4 __attribute__((ext_vector_type(4)));
typedef unsigned short us;

#define MFMA(a,b,c) __builtin_amdgcn_mfma_f32_16x16x32_bf16((a),(b),(c),0,0,0)

__device__ __forceinline__ float bf2f(us u) {
    unsigned v = ((unsigned)u) << 16;
    return __builtin_bit_cast(float, v);
}
__device__ __forceinline__ us f2bf(float f) {
    unsigned u = __builtin_bit_cast(unsigned, f);
    u += 0x7FFFu + ((u >> 16) & 1u);
    return (us)(u >> 16);
}
// truncating bf16 store (folds to ds_write_b16_d16_hi) — R5-proven
__device__ __forceinline__ void stp(us* p, float f) {
    *p = (us)(__builtin_bit_cast(unsigned, f) >> 16);
}
__device__ __forceinline__ void glds16(const us* g, us* l) {
    __builtin_amdgcn_global_load_lds((__attribute__((address_space(1))) void*)g,
                                     (__attribute__((address_space(3))) void*)l, 16, 0, 0);
}

// ---------------------------------------------------------------------------
// Fused input/weight bf16 conversion. x -> xb (float4 idx 0..2097151);
// weights -> wqkvb..wob (contiguous 20 MiB region starting at wqkvb).
// ---------------------------------------------------------------------------
__global__ __launch_bounds__(256) void cvt_all(const float* __restrict__ x,
                                               const float* __restrict__ wq,
                                               const float* __restrict__ wk,
                                               const float* __restrict__ wv,
                                               const float* __restrict__ wo,
                                               us* __restrict__ xb,
                                               us* __restrict__ wdst) {
    int i = blockIdx.x * blockDim.x + threadIdx.x;   // total 4718592 float4s
    const float* src;
    int off;
    if (i < 2097152)      { src = x;  off = 0; }
    else {
        int j = i - 2097152;
        if (j < 1048576)      { src = wq; off = 2097152; }
        else if (j < 1310720) { src = wk; off = 2097152 + 1048576; }
        else if (j < 1572864) { src = wv; off = 2097152 + 1310720; }
        else                  { src = wo; off = 2097152 + 1572864; }
    }
    float4 v = ((const float4*)src)[i - off];
    ushort4 o;
    o.x = f2bf(v.x); o.y = f2bf(v.y); o.z = f2bf(v.z); o.w = f2bf(v.w);
    ((ushort4*)(i < 2097152 ? xb : wdst))[i < 2097152 ? i : i - 2097152] = o;
}

// ---------------------------------------------------------------------------
// R16-validated GEMM (gemm1): 256x256 tile, BK=64, 512 threads (8 waves
// 2Mx4N), 4 phases/K-tile, counted vmcnt (never 0 mid-loop), raw s_barrier,
// both-sides swizzle, T5 setprio. Grid (16,12)=192 blocks (75% fill) —
// R17 A/B proved this beats the 128^2 2-phase 768-block config by ~32us
// (4-phase per-CU rate wins over fill). R18 delta: V columns (n0>=2560,
// blockIdx.y 10-11) write TRANSPOSED directly to vt (b,kvh,d,s) instead of
// qkvbuf — flash never reads V from qkvbuf, and this absorbs transpose_v
// (saves ~8MB traffic + a dispatch). 4 r-values are seq-contiguous -> one
// aligned ushort4 per fragment. No ROPE on V (no block straddles 2560).
// Requires: M%256==0, N%256==0, K%64==0, K/64 >= 3.
// ---------------------------------------------------------------------------
template <typename OutT, bool ROPE>
__global__ __launch_bounds__(512) void gemm_bt2(const us* __restrict__ A, const us* __restrict__ W,
                                                OutT* __restrict__ C, us* __restrict__ vt,
                                                int M, int N, int K) {
    __shared__ us lA[2][2][128 * 64];         // [parity][half][row*64+col]  64 KiB
    __shared__ us lB[2][2][128 * 64];         // 64 KiB
    const int tid = threadIdx.x, lane = tid & 63, wave = tid >> 6;
    const int quad = lane >> 4, lr = lane & 15;
    const int mh = wave >> 2;                 // wave's A half (128-row group)
    const int wnx = wave & 3;                 // wave's 64-col group
    const int bh = wnx >> 1, br0 = (wnx & 1) * 64;
    const int m0 = blockIdx.x * 256, n0 = blockIdx.y * 256;

    const int srow = tid >> 3;
    const int scol = ((tid & 7) ^ (srow & 7)) * 8;   // pre-swizzled global col (elems)
    const int sdst = srow * 64 + (tid & 7) * 8;      // linear LDS dest (elems)

    const us* gA = A + (size_t)m0 * K;
    const us* gB = W + (size_t)n0 * K;

    auto stageH = [&](int s) {
        const int t = s >> 2, ty = s & 3, par = t & 1;
        const us* src;
        us* dst;
        if (ty < 2) { src = gA + (size_t)(ty * 128) * K;       dst = &lA[par][ty][0]; }
        else        { src = gB + (size_t)((ty - 2) * 128) * K; dst = &lB[par][ty - 2][0]; }
        src += t * 64;
        glds16(src + (size_t)srow * K + scol,        dst + sdst);
        glds16(src + (size_t)(srow + 64) * K + scol, dst + sdst + 64 * 64);
    };

    const int rsw = (lr & 7) << 3;            // read-side swizzle (elems); row&7 == lr&7
    auto rdA = [&](int par, int kk, int i) {
        return *(const s16x8*)&lA[par][mh][(i * 16 + lr) * 64 + ((kk * 32 + quad * 8) ^ rsw)];
    };
    auto rdB = [&](int par, int kk, int j) {
        return *(const s16x8*)&lB[par][bh][(br0 + j * 16 + lr) * 64 + ((kk * 32 + quad * 8) ^ rsw)];
    };

    f32x4 acc[8][4] = {};
    const int NT = K / 64;

    stageH(0); stageH(1); stageH(2); stageH(3); stageH(4);
    asm volatile("s_waitcnt vmcnt(2)" ::: "memory");
    __builtin_amdgcn_s_barrier();

    s16x8 af[2][4], ag[2][4], bfr[2][2], bg[2][2];
    for (int t = 0; t < NT; ++t) {
        const int par = t & 1;
        // ---- phase 0: (i 0-3) x (j 0-1) ----
#pragma unroll
        for (int kk = 0; kk < 2; kk++) {
#pragma unroll
            for (int i = 0; i < 4; i++) af[kk][i] = rdA(par, kk, i);
#pragma unroll
            for (int j = 0; j < 2; j++) bfr[kk][j] = rdB(par, kk, j);
        }
        if (t + 1 < NT) stageH(4 * (t + 1) + 1);
        __builtin_amdgcn_s_barrier();
        asm volatile("s_waitcnt lgkmcnt(0)" ::: "memory");
        __builtin_amdgcn_s_setprio(1);
#pragma unroll
        for (int i = 0; i < 4; i++)
#pragma unroll
            for (int j = 0; j < 2; j++)
#pragma unroll
                for (int kk = 0; kk < 2; kk++)
                    acc[i][j] = MFMA(af[kk][i], bfr[kk][j], acc[i][j]);
        __builtin_amdgcn_s_setprio(0);
        __builtin_amdgcn_s_barrier();
        // ---- phase 1: (i 0-3) x (j 2-3) ----
#pragma unroll
        for (int kk = 0; kk < 2; kk++)
#pragma unroll
            for (int j = 0; j < 2; j++) bg[kk][j] = rdB(par, kk, 2 + j);
        if (t + 1 < NT) stageH(4 * (t + 1) + 2);
        __builtin_amdgcn_s_barrier();
        asm volatile("s_waitcnt lgkmcnt(0)" ::: "memory");
        __builtin_amdgcn_s_setprio(1);
#pragma unroll
        for (int i = 0; i < 4; i++)
#pragma unroll
            for (int j = 0; j < 2; j++)
#pragma unroll
                for (int kk = 0; kk < 2; kk++)
                    acc[i][2 + j] = MFMA(af[kk][i], bg[kk][j], acc[i][2 + j]);
        __builtin_amdgcn_s_setprio(0);
        __builtin_amdgcn_s_barrier();
        // ---- phase 2: (i 4-7) x (j 0-1) ----
#pragma unroll
        for (int kk = 0; kk < 2; kk++)
#pragma unroll
            for (int i = 0; i < 4; i++) ag[kk][i] = rdA(par, kk, 4 + i);
        if (t + 1 < NT) stageH(4 * (t + 1) + 3);
        __builtin_amdgcn_s_barrier();
        asm volatile("s_waitcnt lgkmcnt(0)" ::: "memory");
        __builtin_amdgcn_s_setprio(1);
#pragma unroll
        for (int i = 0; i < 4; i++)
#pragma unroll
            for (int j = 0; j < 2; j++)
#pragma unroll
                for (int kk = 0; kk < 2; kk++)
                    acc[4 + i][j] = MFMA(ag[kk][i], bfr[kk][j], acc[4 + i][j]);
        __builtin_amdgcn_s_setprio(0);
        __builtin_amdgcn_s_barrier();
        // ---- phase 3: (i 4-7) x (j 2-3); stage t+2's H0 (parity par, safe) ----
        if (t + 2 < NT) stageH(4 * (t + 2));
        __builtin_amdgcn_s_setprio(1);
#pragma unroll
        for (int i = 0; i < 4; i++)
#pragma unroll
            for (int j = 0; j < 2; j++)
#pragma unroll
                for (int kk = 0; kk < 2; kk++)
                    acc[4 + i][2 + j] = MFMA(ag[kk][i], bg[kk][j], acc[4 + i][2 + j]);
        __builtin_amdgcn_s_setprio(0);
        if (t + 1 < NT) {
            if (t + 2 < NT) asm volatile("s_waitcnt vmcnt(2)" ::: "memory");
            else            asm volatile("s_waitcnt vmcnt(0)" ::: "memory");
            __builtin_amdgcn_s_barrier();
        }
    }

    const bool vblk = ROPE && (n0 >= 2560);   // V block: write transposed to vt
#pragma unroll
    for (int i = 0; i < 8; i++)
#pragma unroll
        for (int j = 0; j < 4; j++) {
            const int row0 = m0 + mh * 128 + i * 16 + quad * 4;
            const int col  = n0 + wnx * 64 + j * 16 + lr;
            if (vblk) {
                const int d = col - 2560;                 // kvh*64 + dd
                const int b = row0 >> 11, s = row0 & (SEQ - 1);
                ushort4 o4;
                o4.x = f2bf(acc[i][j][0]); o4.y = f2bf(acc[i][j][1]);
                o4.z = f2bf(acc[i][j][2]); o4.w = f2bf(acc[i][j][3]);
                *(ushort4*)(vt + ((size_t)b * 512 + d) * SEQ + s) = o4;
            } else {
#pragma unroll
                for (int r = 0; r < 4; r++) {
                    const int row = row0 + r;
                    float v = acc[i][j][r];
                    if (ROPE && n0 < 2560) {
                        int pair = (col >> 1) & 31;
                        float inv = exp2f((float)pair * (-13.2877124f / 32.0f));
                        float ang = (float)(row & (SEQ - 1)) * inv;
                        float c = __cosf(ang), sn = __sinf(ang);
                        float p = __shfl_xor(v, 1);
                        v = v * c + ((col & 1) ? p * sn : -p * sn);
                    }
                    if constexpr (sizeof(OutT) == 2)
                        C[(size_t)row * N + col] = f2bf(v);
                    else
                        C[(size_t)row * N + col] = v;
                }
            }
        }
}

// ---------------------------------------------------------------------------
// R16-validated GEMM (gemm2): 256x128 tile, BK=64, 512 threads (8 waves
// 2Mx4N), 2 phases/K-tile, counted vmcnt, raw s_barrier, both-sides
// swizzle, T5 setprio. Grid (16,16) = 256 blocks = 100% CU fill.
// Requires: M%256==0, N%128==0, K%64==0, K/64 >= 3.
// ---------------------------------------------------------------------------
template <typename OutT>
__global__ __launch_bounds__(512) void gemm_bt2n(const us* __restrict__ A, const us* __restrict__ W,
                                                 OutT* __restrict__ C, int M, int N, int K) {
    __shared__ us lA[2][2][128 * 64];         // 64 KiB
    __shared__ us lB[2][128 * 64];            // 32 KiB
    const int tid = threadIdx.x, lane = tid & 63, wave = tid >> 6;
    const int quad = lane >> 4, lr = lane & 15;
    const int mh = wave >> 2;                 // wave's A half (128-row group)
    const int wnx = wave & 3;                 // wave's 32-col group
    const int m0 = blockIdx.x * 256, n0 = blockIdx.y * 128;

    const int srow = tid >> 3;
    const int scol = ((tid & 7) ^ (srow & 7)) * 8;
    const int sdst = srow * 64 + (tid & 7) * 8;

    const us* gA = A + (size_t)m0 * K;
    const us* gB = W + (size_t)n0 * K;

    // ty: 0=A0, 1=A1, 2=B
    auto stageH = [&](int t, int ty) {
        const int par = t & 1;
        const us* src;
        us* dst;
        if (ty < 2) { src = gA + (size_t)(ty * 128) * K; dst = &lA[par][ty][0]; }
        else        { src = gB;                           dst = &lB[par][0]; }
        src += t * 64;
        glds16(src + (size_t)srow * K + scol,        dst + sdst);
        glds16(src + (size_t)(srow + 64) * K + scol, dst + sdst + 64 * 64);
    };

    const int rsw = (lr & 7) << 3;
    auto rdA = [&](int par, int kk, int i) {
        return *(const s16x8*)&lA[par][mh][(i * 16 + lr) * 64 + ((kk * 32 + quad * 8) ^ rsw)];
    };
    auto rdB = [&](int par, int kk, int j) {
        return *(const s16x8*)&lB[par][(wnx * 32 + j * 16 + lr) * 64 + ((kk * 32 + quad * 8) ^ rsw)];
    };

    f32x4 acc[8][2] = {};
    const int NT = K / 64;

    // prologue: tile0 {A0,A1,B} + tile1 A0 -> wait all but newest half
    stageH(0, 0); stageH(0, 1); stageH(0, 2); stageH(1, 0);
    asm volatile("s_waitcnt vmcnt(2)" ::: "memory");
    __builtin_amdgcn_s_barrier();

    s16x8 af[2][4], ag[2][4], bfr[2][2];
    for (int t = 0; t < NT; ++t) {
        const int par = t & 1;
        // ---- phase 0: (i 0-3) x (j 0-1) ----
#pragma unroll
        for (int kk = 0; kk < 2; kk++) {
#pragma unroll
            for (int i = 0; i < 4; i++) af[kk][i] = rdA(par, kk, i);
#pragma unroll
            for (int j = 0; j < 2; j++) bfr[kk][j] = rdB(par, kk, j);
        }
        if (t + 1 < NT) stageH(t + 1, 1);
        __builtin_amdgcn_s_barrier();
        asm volatile("s_waitcnt lgkmcnt(0)" ::: "memory");
        __builtin_amdgcn_s_setprio(1);
#pragma unroll
        for (int i = 0; i < 4; i++)
#pragma unroll
            for (int j = 0; j < 2; j++)
#pragma unroll
                for (int kk = 0; kk < 2; kk++)
                    acc[i][j] = MFMA(af[kk][i], bfr[kk][j], acc[i][j]);
        __builtin_amdgcn_s_setprio(0);
        __builtin_amdgcn_s_barrier();
        // ---- phase 1: (i 4-7) x (j 0-1); then stage t+2.A0 (parity par, safe) ----
#pragma unroll
        for (int kk = 0; kk < 2; kk++)
#pragma unroll
            for (int i = 0; i < 4; i++) ag[kk][i] = rdA(par, kk, 4 + i);
        if (t + 1 < NT) stageH(t + 1, 2);
        __builtin_amdgcn_s_barrier();
        asm volatile("s_waitcnt lgkmcnt(0)" ::: "memory");
        __builtin_amdgcn_s_setprio(1);
#pragma unroll
        for (int i = 0; i < 4; i++)
#pragma unroll
            for (int j = 0; j < 2; j++)
#pragma unroll
                for (int kk = 0; kk < 2; kk++)
                    acc[4 + i][j] = MFMA(ag[kk][i], bfr[kk][j], acc[4 + i][j]);
        __builtin_amdgcn_s_setprio(0);
        if (t + 2 < NT) stageH(t + 2, 0);
        if (t + 1 < NT) {
            if (t + 2 < NT) asm volatile("s_waitcnt vmcnt(2)" ::: "memory");
            else            asm volatile("s_waitcnt vmcnt(0)" ::: "memory");
            __builtin_amdgcn_s_barrier();
        }
    }

#pragma unroll
    for (int i = 0; i < 8; i++)
#pragma unroll
        for (int j = 0; j < 2; j++)
#pragma unroll
            for (int r = 0; r < 4; r++) {
                int row = m0 + mh * 128 + i * 16 + quad * 4 + r;
                int col = n0 + wnx * 32 + j * 16 + lr;
                if constexpr (sizeof(OutT) == 2)
                    C[(size_t)row * N + col] = f2bf(acc[i][j][r]);
                else
                    C[(size_t)row * N + col] = acc[i][j][r];
            }
}

// ---------------------------------------------------------------------------
// Causal flash attention — R6 4-tile structure + V phase-shift (proven
// neutral, kept). Occupancy RF-pinned at 2 waves/SIMD (unified VGPR+AGPR
// cap 256/wave; this kernel ~200). kf prefetch after last QK use; vf(kb+1)
// at loop bottom after PV. Both K/V global-latency hypotheses measured null
// -> remaining idle is structural; fixing it = swapped-QK rewrite (future).
// P-store scheme = R5-proven scalar stp + lgkmcnt(0). l via ones-col MFMA.
// R17 confirmed: R16's 135us was environmental; stable value is ~123.
// ---------------------------------------------------------------------------
__global__ __launch_bounds__(256, 2) void flash_attn(const us* __restrict__ qkv,
                                                     const us* __restrict__ vt,
                                                     us* __restrict__ o) {
    __shared__ us P[4][4][16 * 72];           // [wave][tile]
    const int bh = blockIdx.y, b = bh >> 5, h = bh & 31, kvh = h >> 2;
    const int wave = threadIdx.x >> 6, lane = threadIdx.x & 63;
    const int quad = lane >> 4, lr = lane & 15;
    const int p = ((int)blockIdx.x + (int)(blockIdx.y >> 3)) & 7;
    const int qts[4] = {p, 15 - p, 16 + p, 31 - p};
    const us* kbase = qkv + (size_t)b * SEQ * QKVN + 2048 + kvh * 64;
    const us* vb = vt + (size_t)(b * 8 + kvh) * VTR * SEQ;
    const float QS = 0.125f * 1.44269504f;    // scale * log2(e)

    s16x8 onesb;
    const short ov = (lr == 0) ? (short)0x3F80 : (short)0;
#pragma unroll
    for (int j = 0; j < 8; j++) onesb[j] = ov;

    int q0[4];
    s16x8 qa[4][2];
#pragma unroll
    for (int t = 0; t < 4; t++) {
        q0[t] = qts[t] * 64 + wave * 16;
        const us* qb = qkv + (size_t)(b * SEQ + q0[t]) * QKVN + h * 64;
        qa[t][0] = *(const s16x8*)(qb + (size_t)lr * QKVN + quad * 8);
        qa[t][1] = *(const s16x8*)(qb + (size_t)lr * QKVN + 32 + quad * 8);
#pragma unroll
        for (int j = 0; j < 8; j++) {
            qa[t][0][j] = (short)f2bf(bf2f((us)qa[t][0][j]) * QS);
            qa[t][1][j] = (short)f2bf(bf2f((us)qa[t][1][j]) * QS);
        }
    }

    f32x4 oacc[4][5] = {};                    // per tile: [0..3]=O, [4] col0 = l
    s16x8 kf[8], vf[8];
    {
        const us* kp = kbase + (size_t)lr * QKVN;
#pragma unroll
        for (int nb = 0; nb < 4; nb++) {
            kf[2 * nb]     = *(const s16x8*)(kp + (size_t)nb * 16 * QKVN + quad * 8);
            kf[2 * nb + 1] = *(const s16x8*)(kp + (size_t)nb * 16 * QKVN + 32 + quad * 8);
        }
#pragma unroll
        for (int n = 0; n < 4; n++)
#pragma unroll
            for (int kc = 0; kc < 2; kc++)
                vf[n * 2 + kc] = *(const s16x8*)(vb + (size_t)(n * 16 + lr) * SEQ +
                                                 kc * 32 + quad * 8);
    }

    // QK for one tile -> sc; exp2 -> P[wave][t] (scalar b16 stores, R5-proven)
    auto qk_tile = [&](int t, f32x4* sc) {
#pragma unroll
        for (int nb = 0; nb < 4; nb++) {
            sc[nb] = f32x4{0.f, 0.f, 0.f, 0.f};
            sc[nb] = MFMA(qa[t][0], kf[2 * nb], sc[nb]);
            sc[nb] = MFMA(qa[t][1], kf[2 * nb + 1], sc[nb]);
        }
    };
    auto store_tile = [&](int t, const f32x4* sc, int kb) {
        us* Pt = &P[wave][t][0];
        if (kb == qts[t]) {                   // diagonal block: causal mask
#pragma unroll
            for (int nb = 0; nb < 4; nb++)
#pragma unroll
                for (int r = 0; r < 4; r++) {
                    int key = kb * 64 + nb * 16 + lr, row = q0[t] + quad * 4 + r;
                    float s = (key > row) ? -1e30f : sc[nb][r];
                    stp(&Pt[(quad * 4 + r) * 72 + nb * 16 + lr], exp2f(s));
                }
        } else {
#pragma unroll
            for (int nb = 0; nb < 4; nb++)
#pragma unroll
                for (int r = 0; r < 4; r++)
                    stp(&Pt[(quad * 4 + r) * 72 + nb * 16 + lr], exp2f(sc[nb][r]));
        }
    };

    const int kbmax = qts[3];
    for (int kb = 0; kb <= kbmax; kb++) {
        const bool a0 = (kb <= qts[0]), a1 = (kb <= qts[1]), a2 = (kb <= qts[2]);
        f32x4 sa[4], sb[4];
        // ---- QK pair 1 (tiles 0,1) with current kf ----
        if (a0) qk_tile(0, sa);
        if (a1) qk_tile(1, sb);
        if (a0) store_tile(0, sa, kb);
        if (a1) store_tile(1, sb, kb);
        // ---- QK pair 2 (tiles 2,3) still with current kf ----
        if (a2) qk_tile(2, sa);
        qk_tile(3, sb);                       // tile 3 always active
        // ---- kf prefetch for kb+1 (kf now dead until next iteration) ----
        if (kb < kbmax) {
            const us* kp = kbase + (size_t)((kb + 1) * 64 + lr) * QKVN;
#pragma unroll
            for (int nb = 0; nb < 4; nb++) {
                kf[2 * nb]     = *(const s16x8*)(kp + (size_t)nb * 16 * QKVN + quad * 8);
                kf[2 * nb + 1] = *(const s16x8*)(kp + (size_t)nb * 16 * QKVN + 32 + quad * 8);
            }
        }
        if (a2) store_tile(2, sa, kb);
        store_tile(3, sb, kb);
        asm volatile("s_waitcnt lgkmcnt(0)" ::: "memory");   // wave-private tiles
        // ---- PV for all active tiles, shared vf (loaded one iter ahead) ----
        __builtin_amdgcn_s_setprio(1);
#pragma unroll
        for (int t = 0; t < 4; t++) {
            if (kb <= qts[t]) {
#pragma unroll
                for (int kc = 0; kc < 2; kc++) {
                    s16x8 pa = *(const s16x8*)&P[wave][t][lr * 72 + kc * 32 + quad * 8];
#pragma unroll
                    for (int n = 0; n < 4; n++)
                        oacc[t][n] = MFMA(pa, vf[n * 2 + kc], oacc[t][n]);
                    oacc[t][4] = MFMA(pa, onesb, oacc[t][4]);
                }
            }
        }
        __builtin_amdgcn_s_setprio(0);
        // ---- vf load for kb+1 (vf dead after PV; full next-QK-phase cover) ----
        if (kb < kbmax) {
#pragma unroll
            for (int n = 0; n < 4; n++)
#pragma unroll
                for (int kc = 0; kc < 2; kc++)
                    vf[n * 2 + kc] = *(const s16x8*)(vb + (size_t)(n * 16 + lr) * SEQ +
                                                     (kb + 1) * 64 + kc * 32 + quad * 8);
        }
    }

#pragma unroll
    for (int t = 0; t < 4; t++)
#pragma unroll
        for (int r = 0; r < 4; r++) {
            float l = __shfl(oacc[t][4][r], lane & 48);
            float li = 1.0f / l;
#pragma unroll
            for (int n = 0; n < 4; n++)
                o[(size_t)(b * SEQ + q0[t] + quad * 4 + r) * DM + h * 64 + n * 16 + lr] =
                    f2bf(oacc[t][n][r] * li);
        }
}

// ---------------------------------------------------------------------------
extern "C" void kernel_launch(void* const* d_in, const int* in_sizes, int n_in,
                              void* d_out, int out_size, void* d_ws, size_t ws_size,
                              hipStream_t stream) {
    const float* x  = (const float*)d_in[0];
    const float* wq = (const float*)d_in[1];
    const float* wk = (const float*)d_in[2];
    const float* wv = (const float*)d_in[3];
    const float* wo = (const float*)d_in[4];
    float* out = (float*)d_out;

    char* ws = (char*)d_ws;
    const size_t MB = 1024 * 1024;
    us* xb     = (us*)(ws + 0 * MB);    // 16 MiB; reused as abuf (flash out)
    us* abuf   = (us*)(ws + 0 * MB);
    us* wqkvb  = (us*)(ws + 16 * MB);   // 12 MiB (wq|wk|wv) — contiguous with wob
    us* wob    = (us*)(ws + 28 * MB);   // 8 MiB
    us* qkvbuf = (us*)(ws + 36 * MB);   // 24 MiB (4096 x 3072; V cols unused now)
    us* vtbuf  = (us*)(ws + 60 * MB);   // 4 MiB (written by gemm1 epilogue)

    dim3 blk(256);
    cvt_all<<<dim3(18432), blk, 0, stream>>>(x, wq, wk, wv, wo, xb, wqkvb);

    gemm_bt2<us, true><<<dim3(16, 12), dim3(512), 0, stream>>>(xb, wqkvb, qkvbuf, vtbuf,
                                                               4096, 3072, 2048);
    flash_attn<<<dim3(8, 64), blk, 0, stream>>>(qkvbuf, vtbuf, abuf);
    gemm_bt2n<float><<<dim3(16, 16), dim3(512), 0, stream>>>(abuf, wob, out, 4096, 2048, 2048);
}

// Round 14
// 339.774 us; speedup vs baseline: 1.0728x; 1.0057x over previous
//
#include <hip/hip_runtime.h>

#define SEQ    2048
#define DM     2048
#define QKVN   3072
#define VTR    64

typedef short s16x8 __attribute__((ext_vector_type(8)));
typedef float f32x4 __attribute__((ext_vector_type(4)));
typedef unsigned short us;

#define MFMA(a,b,c) __builtin_amdgcn_mfma_f32_16x16x32_bf16((a),(b),(c),0,0,0)

__device__ __forceinline__ float bf2f(us u) {
    unsigned v = ((unsigned)u) << 16;
    return __builtin_bit_cast(float, v);
}
__device__ __forceinline__ us f2bf(float f) {
    unsigned u = __builtin_bit_cast(unsigned, f);
    u += 0x7FFFu + ((u >> 16) & 1u);
    return (us)(u >> 16);
}
// truncating bf16 store (folds to ds_write_b16_d16_hi) — R5-proven
__device__ __forceinline__ void stp(us* p, float f) {
    *p = (us)(__builtin_bit_cast(unsigned, f) >> 16);
}
__device__ __forceinline__ void glds16(const us* g, us* l) {
    __builtin_amdgcn_global_load_lds((__attribute__((address_space(1))) void*)g,
                                     (__attribute__((address_space(3))) void*)l, 16, 0, 0);
}

// ---------------------------------------------------------------------------
// Fused input/weight bf16 conversion, R19: 2 float4 per thread -> one 16B
// packed store (was 1 float4 -> 8B store; 3.3 TB/s read-side, half the
// achievable ceiling). All region sizes are even in float4 units, so a
// pair never straddles a region boundary. Grid 9216 x 256.
// ---------------------------------------------------------------------------
__global__ __launch_bounds__(256) void cvt_all(const float* __restrict__ x,
                                               const float* __restrict__ wq,
                                               const float* __restrict__ wk,
                                               const float* __restrict__ wv,
                                               const float* __restrict__ wo,
                                               us* __restrict__ xb,
                                               us* __restrict__ wdst) {
    int i = (blockIdx.x * blockDim.x + threadIdx.x) * 2;   // float4 idx, 4718592 total
    const float* src;
    int off;
    if (i < 2097152)      { src = x;  off = 0; }
    else {
        int j = i - 2097152;
        if (j < 1048576)      { src = wq; off = 2097152; }
        else if (j < 1310720) { src = wk; off = 2097152 + 1048576; }
        else if (j < 1572864) { src = wv; off = 2097152 + 1310720; }
        else                  { src = wo; off = 2097152 + 1572864; }
    }
    const int base = i - off;
    float4 v0 = ((const float4*)src)[base];
    float4 v1 = ((const float4*)src)[base + 1];
    s16x8 o;
    o[0] = (short)f2bf(v0.x); o[1] = (short)f2bf(v0.y);
    o[2] = (short)f2bf(v0.z); o[3] = (short)f2bf(v0.w);
    o[4] = (short)f2bf(v1.x); o[5] = (short)f2bf(v1.y);
    o[6] = (short)f2bf(v1.z); o[7] = (short)f2bf(v1.w);
    us* d = (i < 2097152) ? xb : wdst;
    const int di = (i < 2097152) ? i : i - 2097152;
    *(s16x8*)(d + di * 4) = o;                // 16B aligned (di even)
}

// ---------------------------------------------------------------------------
// R16-validated GEMM (gemm1): 256x256 tile, BK=64, 512 threads (8 waves
// 2Mx4N), 4 phases/K-tile, counted vmcnt (never 0 mid-loop), raw s_barrier,
// both-sides swizzle, T5 setprio. Grid (16,12)=192 blocks (75% fill) —
// R17 A/B proved this beats the 128^2 2-phase 768-block config by ~32us.
// R18 (validated): V columns (n0>=2560) write TRANSPOSED directly to vt —
// absorbs transpose_v (saves ~8MB traffic + a dispatch). No ROPE on V.
// Requires: M%256==0, N%256==0, K%64==0, K/64 >= 3.
// ---------------------------------------------------------------------------
template <typename OutT, bool ROPE>
__global__ __launch_bounds__(512) void gemm_bt2(const us* __restrict__ A, const us* __restrict__ W,
                                                OutT* __restrict__ C, us* __restrict__ vt,
                                                int M, int N, int K) {
    __shared__ us lA[2][2][128 * 64];         // [parity][half][row*64+col]  64 KiB
    __shared__ us lB[2][2][128 * 64];         // 64 KiB
    const int tid = threadIdx.x, lane = tid & 63, wave = tid >> 6;
    const int quad = lane >> 4, lr = lane & 15;
    const int mh = wave >> 2;                 // wave's A half (128-row group)
    const int wnx = wave & 3;                 // wave's 64-col group
    const int bh = wnx >> 1, br0 = (wnx & 1) * 64;
    const int m0 = blockIdx.x * 256, n0 = blockIdx.y * 256;

    const int srow = tid >> 3;
    const int scol = ((tid & 7) ^ (srow & 7)) * 8;   // pre-swizzled global col (elems)
    const int sdst = srow * 64 + (tid & 7) * 8;      // linear LDS dest (elems)

    const us* gA = A + (size_t)m0 * K;
    const us* gB = W + (size_t)n0 * K;

    auto stageH = [&](int s) {
        const int t = s >> 2, ty = s & 3, par = t & 1;
        const us* src;
        us* dst;
        if (ty < 2) { src = gA + (size_t)(ty * 128) * K;       dst = &lA[par][ty][0]; }
        else        { src = gB + (size_t)((ty - 2) * 128) * K; dst = &lB[par][ty - 2][0]; }
        src += t * 64;
        glds16(src + (size_t)srow * K + scol,        dst + sdst);
        glds16(src + (size_t)(srow + 64) * K + scol, dst + sdst + 64 * 64);
    };

    const int rsw = (lr & 7) << 3;            // read-side swizzle (elems); row&7 == lr&7
    auto rdA = [&](int par, int kk, int i) {
        return *(const s16x8*)&lA[par][mh][(i * 16 + lr) * 64 + ((kk * 32 + quad * 8) ^ rsw)];
    };
    auto rdB = [&](int par, int kk, int j) {
        return *(const s16x8*)&lB[par][bh][(br0 + j * 16 + lr) * 64 + ((kk * 32 + quad * 8) ^ rsw)];
    };

    f32x4 acc[8][4] = {};
    const int NT = K / 64;

    stageH(0); stageH(1); stageH(2); stageH(3); stageH(4);
    asm volatile("s_waitcnt vmcnt(2)" ::: "memory");
    __builtin_amdgcn_s_barrier();

    s16x8 af[2][4], ag[2][4], bfr[2][2], bg[2][2];
    for (int t = 0; t < NT; ++t) {
        const int par = t & 1;
        // ---- phase 0: (i 0-3) x (j 0-1) ----
#pragma unroll
        for (int kk = 0; kk < 2; kk++) {
#pragma unroll
            for (int i = 0; i < 4; i++) af[kk][i] = rdA(par, kk, i);
#pragma unroll
            for (int j = 0; j < 2; j++) bfr[kk][j] = rdB(par, kk, j);
        }
        if (t + 1 < NT) stageH(4 * (t + 1) + 1);
        __builtin_amdgcn_s_barrier();
        asm volatile("s_waitcnt lgkmcnt(0)" ::: "memory");
        __builtin_amdgcn_s_setprio(1);
#pragma unroll
        for (int i = 0; i < 4; i++)
#pragma unroll
            for (int j = 0; j < 2; j++)
#pragma unroll
                for (int kk = 0; kk < 2; kk++)
                    acc[i][j] = MFMA(af[kk][i], bfr[kk][j], acc[i][j]);
        __builtin_amdgcn_s_setprio(0);
        __builtin_amdgcn_s_barrier();
        // ---- phase 1: (i 0-3) x (j 2-3) ----
#pragma unroll
        for (int kk = 0; kk < 2; kk++)
#pragma unroll
            for (int j = 0; j < 2; j++) bg[kk][j] = rdB(par, kk, 2 + j);
        if (t + 1 < NT) stageH(4 * (t + 1) + 2);
        __builtin_amdgcn_s_barrier();
        asm volatile("s_waitcnt lgkmcnt(0)" ::: "memory");
        __builtin_amdgcn_s_setprio(1);
#pragma unroll
        for (int i = 0; i < 4; i++)
#pragma unroll
            for (int j = 0; j < 2; j++)
#pragma unroll
                for (int kk = 0; kk < 2; kk++)
                    acc[i][2 + j] = MFMA(af[kk][i], bg[kk][j], acc[i][2 + j]);
        __builtin_amdgcn_s_setprio(0);
        __builtin_amdgcn_s_barrier();
        // ---- phase 2: (i 4-7) x (j 0-1) ----
#pragma unroll
        for (int kk = 0; kk < 2; kk++)
#pragma unroll
            for (int i = 0; i < 4; i++) ag[kk][i] = rdA(par, kk, 4 + i);
        if (t + 1 < NT) stageH(4 * (t + 1) + 3);
        __builtin_amdgcn_s_barrier();
        asm volatile("s_waitcnt lgkmcnt(0)" ::: "memory");
        __builtin_amdgcn_s_setprio(1);
#pragma unroll
        for (int i = 0; i < 4; i++)
#pragma unroll
            for (int j = 0; j < 2; j++)
#pragma unroll
                for (int kk = 0; kk < 2; kk++)
                    acc[4 + i][j] = MFMA(ag[kk][i], bfr[kk][j], acc[4 + i][j]);
        __builtin_amdgcn_s_setprio(0);
        __builtin_amdgcn_s_barrier();
        // ---- phase 3: (i 4-7) x (j 2-3); stage t+2's H0 (parity par, safe) ----
        if (t + 2 < NT) stageH(4 * (t + 2));
        __builtin_amdgcn_s_setprio(1);
#pragma unroll
        for (int i = 0; i < 4; i++)
#pragma unroll
            for (int j = 0; j < 2; j++)
#pragma unroll
                for (int kk = 0; kk < 2; kk++)
                    acc[4 + i][2 + j] = MFMA(ag[kk][i], bg[kk][j], acc[4 + i][2 + j]);
        __builtin_amdgcn_s_setprio(0);
        if (t + 1 < NT) {
            if (t + 2 < NT) asm volatile("s_waitcnt vmcnt(2)" ::: "memory");
            else            asm volatile("s_waitcnt vmcnt(0)" ::: "memory");
            __builtin_amdgcn_s_barrier();
        }
    }

    const bool vblk = ROPE && (n0 >= 2560);   // V block: write transposed to vt
#pragma unroll
    for (int i = 0; i < 8; i++)
#pragma unroll
        for (int j = 0; j < 4; j++) {
            const int row0 = m0 + mh * 128 + i * 16 + quad * 4;
            const int col  = n0 + wnx * 64 + j * 16 + lr;
            if (vblk) {
                const int d = col - 2560;                 // kvh*64 + dd
                const int b = row0 >> 11, s = row0 & (SEQ - 1);
                ushort4 o4;
                o4.x = f2bf(acc[i][j][0]); o4.y = f2bf(acc[i][j][1]);
                o4.z = f2bf(acc[i][j][2]); o4.w = f2bf(acc[i][j][3]);
                *(ushort4*)(vt + ((size_t)b * 512 + d) * SEQ + s) = o4;
            } else {
#pragma unroll
                for (int r = 0; r < 4; r++) {
                    const int row = row0 + r;
                    float v = acc[i][j][r];
                    if (ROPE && n0 < 2560) {
                        int pair = (col >> 1) & 31;
                        float inv = exp2f((float)pair * (-13.2877124f / 32.0f));
                        float ang = (float)(row & (SEQ - 1)) * inv;
                        float c = __cosf(ang), sn = __sinf(ang);
                        float p = __shfl_xor(v, 1);
                        v = v * c + ((col & 1) ? p * sn : -p * sn);
                    }
                    if constexpr (sizeof(OutT) == 2)
                        C[(size_t)row * N + col] = f2bf(v);
                    else
                        C[(size_t)row * N + col] = v;
                }
            }
        }
}

// ---------------------------------------------------------------------------
// R16-validated GEMM (gemm2): 256x128 tile, BK=64, 512 threads (8 waves
// 2Mx4N), 2 phases/K-tile, counted vmcnt, raw s_barrier, both-sides
// swizzle, T5 setprio. Grid (16,16) = 256 blocks = 100% CU fill.
// Requires: M%256==0, N%128==0, K%64==0, K/64 >= 3.
// ---------------------------------------------------------------------------
template <typename OutT>
__global__ __launch_bounds__(512) void gemm_bt2n(const us* __restrict__ A, const us* __restrict__ W,
                                                 OutT* __restrict__ C, int M, int N, int K) {
    __shared__ us lA[2][2][128 * 64];         // 64 KiB
    __shared__ us lB[2][128 * 64];            // 32 KiB
    const int tid = threadIdx.x, lane = tid & 63, wave = tid >> 6;
    const int quad = lane >> 4, lr = lane & 15;
    const int mh = wave >> 2;                 // wave's A half (128-row group)
    const int wnx = wave & 3;                 // wave's 32-col group
    const int m0 = blockIdx.x * 256, n0 = blockIdx.y * 128;

    const int srow = tid >> 3;
    const int scol = ((tid & 7) ^ (srow & 7)) * 8;
    const int sdst = srow * 64 + (tid & 7) * 8;

    const us* gA = A + (size_t)m0 * K;
    const us* gB = W + (size_t)n0 * K;

    // ty: 0=A0, 1=A1, 2=B
    auto stageH = [&](int t, int ty) {
        const int par = t & 1;
        const us* src;
        us* dst;
        if (ty < 2) { src = gA + (size_t)(ty * 128) * K; dst = &lA[par][ty][0]; }
        else        { src = gB;                           dst = &lB[par][0]; }
        src += t * 64;
        glds16(src + (size_t)srow * K + scol,        dst + sdst);
        glds16(src + (size_t)(srow + 64) * K + scol, dst + sdst + 64 * 64);
    };

    const int rsw = (lr & 7) << 3;
    auto rdA = [&](int par, int kk, int i) {
        return *(const s16x8*)&lA[par][mh][(i * 16 + lr) * 64 + ((kk * 32 + quad * 8) ^ rsw)];
    };
    auto rdB = [&](int par, int kk, int j) {
        return *(const s16x8*)&lB[par][(wnx * 32 + j * 16 + lr) * 64 + ((kk * 32 + quad * 8) ^ rsw)];
    };

    f32x4 acc[8][2] = {};
    const int NT = K / 64;

    // prologue: tile0 {A0,A1,B} + tile1 A0 -> wait all but newest half
    stageH(0, 0); stageH(0, 1); stageH(0, 2); stageH(1, 0);
    asm volatile("s_waitcnt vmcnt(2)" ::: "memory");
    __builtin_amdgcn_s_barrier();

    s16x8 af[2][4], ag[2][4], bfr[2][2];
    for (int t = 0; t < NT; ++t) {
        const int par = t & 1;
        // ---- phase 0: (i 0-3) x (j 0-1) ----
#pragma unroll
        for (int kk = 0; kk < 2; kk++) {
#pragma unroll
            for (int i = 0; i < 4; i++) af[kk][i] = rdA(par, kk, i);
#pragma unroll
            for (int j = 0; j < 2; j++) bfr[kk][j] = rdB(par, kk, j);
        }
        if (t + 1 < NT) stageH(t + 1, 1);
        __builtin_amdgcn_s_barrier();
        asm volatile("s_waitcnt lgkmcnt(0)" ::: "memory");
        __builtin_amdgcn_s_setprio(1);
#pragma unroll
        for (int i = 0; i < 4; i++)
#pragma unroll
            for (int j = 0; j < 2; j++)
#pragma unroll
                for (int kk = 0; kk < 2; kk++)
                    acc[i][j] = MFMA(af[kk][i], bfr[kk][j], acc[i][j]);
        __builtin_amdgcn_s_setprio(0);
        __builtin_amdgcn_s_barrier();
        // ---- phase 1: (i 4-7) x (j 0-1); then stage t+2.A0 (parity par, safe) ----
#pragma unroll
        for (int kk = 0; kk < 2; kk++)
#pragma unroll
            for (int i = 0; i < 4; i++) ag[kk][i] = rdA(par, kk, 4 + i);
        if (t + 1 < NT) stageH(t + 1, 2);
        __builtin_amdgcn_s_barrier();
        asm volatile("s_waitcnt lgkmcnt(0)" ::: "memory");
        __builtin_amdgcn_s_setprio(1);
#pragma unroll
        for (int i = 0; i < 4; i++)
#pragma unroll
            for (int j = 0; j < 2; j++)
#pragma unroll
                for (int kk = 0; kk < 2; kk++)
                    acc[4 + i][j] = MFMA(ag[kk][i], bfr[kk][j], acc[4 + i][j]);
        __builtin_amdgcn_s_setprio(0);
        if (t + 2 < NT) stageH(t + 2, 0);
        if (t + 1 < NT) {
            if (t + 2 < NT) asm volatile("s_waitcnt vmcnt(2)" ::: "memory");
            else            asm volatile("s_waitcnt vmcnt(0)" ::: "memory");
            __builtin_amdgcn_s_barrier();
        }
    }

#pragma unroll
    for (int i = 0; i < 8; i++)
#pragma unroll
        for (int j = 0; j < 2; j++)
#pragma unroll
            for (int r = 0; r < 4; r++) {
                int row = m0 + mh * 128 + i * 16 + quad * 4 + r;
                int col = n0 + wnx * 32 + j * 16 + lr;
                if constexpr (sizeof(OutT) == 2)
                    C[(size_t)row * N + col] = f2bf(acc[i][j][r]);
                else
                    C[(size_t)row * N + col] = acc[i][j][r];
            }
}

// ---------------------------------------------------------------------------
// Causal flash attention — R6 4-tile structure + V phase-shift (proven
// neutral, kept). Occupancy RF-pinned at 2 waves/SIMD (unified VGPR+AGPR
// cap 256/wave; this kernel ~200). kf prefetch after last QK use; vf(kb+1)
// at loop bottom after PV. Both K/V global-latency hypotheses measured null
// -> remaining idle is structural; fixing it = 32x32 swapped-QK rewrite.
// P-store scheme = R5-proven scalar stp + lgkmcnt(0). l via ones-col MFMA.
// Stable at ~123-124us (R16's 135 was environmental).
// ---------------------------------------------------------------------------
__global__ __launch_bounds__(256, 2) void flash_attn(const us* __restrict__ qkv,
                                                     const us* __restrict__ vt,
                                                     us* __restrict__ o) {
    __shared__ us P[4][4][16 * 72];           // [wave][tile]
    const int bh = blockIdx.y, b = bh >> 5, h = bh & 31, kvh = h >> 2;
    const int wave = threadIdx.x >> 6, lane = threadIdx.x & 63;
    const int quad = lane >> 4, lr = lane & 15;
    const int p = ((int)blockIdx.x + (int)(blockIdx.y >> 3)) & 7;
    const int qts[4] = {p, 15 - p, 16 + p, 31 - p};
    const us* kbase = qkv + (size_t)b * SEQ * QKVN + 2048 + kvh * 64;
    const us* vb = vt + (size_t)(b * 8 + kvh) * VTR * SEQ;
    const float QS = 0.125f * 1.44269504f;    // scale * log2(e)

    s16x8 onesb;
    const short ov = (lr == 0) ? (short)0x3F80 : (short)0;
#pragma unroll
    for (int j = 0; j < 8; j++) onesb[j] = ov;

    int q0[4];
    s16x8 qa[4][2];
#pragma unroll
    for (int t = 0; t < 4; t++) {
        q0[t] = qts[t] * 64 + wave * 16;
        const us* qb = qkv + (size_t)(b * SEQ + q0[t]) * QKVN + h * 64;
        qa[t][0] = *(const s16x8*)(qb + (size_t)lr * QKVN + quad * 8);
        qa[t][1] = *(const s16x8*)(qb + (size_t)lr * QKVN + 32 + quad * 8);
#pragma unroll
        for (int j = 0; j < 8; j++) {
            qa[t][0][j] = (short)f2bf(bf2f((us)qa[t][0][j]) * QS);
            qa[t][1][j] = (short)f2bf(bf2f((us)qa[t][1][j]) * QS);
        }
    }

    f32x4 oacc[4][5] = {};                    // per tile: [0..3]=O, [4] col0 = l
    s16x8 kf[8], vf[8];
    {
        const us* kp = kbase + (size_t)lr * QKVN;
#pragma unroll
        for (int nb = 0; nb < 4; nb++) {
            kf[2 * nb]     = *(const s16x8*)(kp + (size_t)nb * 16 * QKVN + quad * 8);
            kf[2 * nb + 1] = *(const s16x8*)(kp + (size_t)nb * 16 * QKVN + 32 + quad * 8);
        }
#pragma unroll
        for (int n = 0; n < 4; n++)
#pragma unroll
            for (int kc = 0; kc < 2; kc++)
                vf[n * 2 + kc] = *(const s16x8*)(vb + (size_t)(n * 16 + lr) * SEQ +
                                                 kc * 32 + quad * 8);
    }

    // QK for one tile -> sc; exp2 -> P[wave][t] (scalar b16 stores, R5-proven)
    auto qk_tile = [&](int t, f32x4* sc) {
#pragma unroll
        for (int nb = 0; nb < 4; nb++) {
            sc[nb] = f32x4{0.f, 0.f, 0.f, 0.f};
            sc[nb] = MFMA(qa[t][0], kf[2 * nb], sc[nb]);
            sc[nb] = MFMA(qa[t][1], kf[2 * nb + 1], sc[nb]);
        }
    };
    auto store_tile = [&](int t, const f32x4* sc, int kb) {
        us* Pt = &P[wave][t][0];
        if (kb == qts[t]) {                   // diagonal block: causal mask
#pragma unroll
            for (int nb = 0; nb < 4; nb++)
#pragma unroll
                for (int r = 0; r < 4; r++) {
                    int key = kb * 64 + nb * 16 + lr, row = q0[t] + quad * 4 + r;
                    float s = (key > row) ? -1e30f : sc[nb][r];
                    stp(&Pt[(quad * 4 + r) * 72 + nb * 16 + lr], exp2f(s));
                }
        } else {
#pragma unroll
            for (int nb = 0; nb < 4; nb++)
#pragma unroll
                for (int r = 0; r < 4; r++)
                    stp(&Pt[(quad * 4 + r) * 72 + nb * 16 + lr], exp2f(sc[nb][r]));
        }
    };

    const int kbmax = qts[3];
    for (int kb = 0; kb <= kbmax; kb++) {
        const bool a0 = (kb <= qts[0]), a1 = (kb <= qts[1]), a2 = (kb <= qts[2]);
        f32x4 sa[4], sb[4];
        // ---- QK pair 1 (tiles 0,1) with current kf ----
        if (a0) qk_tile(0, sa);
        if (a1) qk_tile(1, sb);
        if (a0) store_tile(0, sa, kb);
        if (a1) store_tile(1, sb, kb);
        // ---- QK pair 2 (tiles 2,3) still with current kf ----
        if (a2) qk_tile(2, sa);
        qk_tile(3, sb);                       // tile 3 always active
        // ---- kf prefetch for kb+1 (kf now dead until next iteration) ----
        if (kb < kbmax) {
            const us* kp = kbase + (size_t)((kb + 1) * 64 + lr) * QKVN;
#pragma unroll
            for (int nb = 0; nb < 4; nb++) {
                kf[2 * nb]     = *(const s16x8*)(kp + (size_t)nb * 16 * QKVN + quad * 8);
                kf[2 * nb + 1] = *(const s16x8*)(kp + (size_t)nb * 16 * QKVN + 32 + quad * 8);
            }
        }
        if (a2) store_tile(2, sa, kb);
        store_tile(3, sb, kb);
        asm volatile("s_waitcnt lgkmcnt(0)" ::: "memory");   // wave-private tiles
        // ---- PV for all active tiles, shared vf (loaded one iter ahead) ----
        __builtin_amdgcn_s_setprio(1);
#pragma unroll
        for (int t = 0; t < 4; t++) {
            if (kb <= qts[t]) {
#pragma unroll
                for (int kc = 0; kc < 2; kc++) {
                    s16x8 pa = *(const s16x8*)&P[wave][t][lr * 72 + kc * 32 + quad * 8];
#pragma unroll
                    for (int n = 0; n < 4; n++)
                        oacc[t][n] = MFMA(pa, vf[n * 2 + kc], oacc[t][n]);
                    oacc[t][4] = MFMA(pa, onesb, oacc[t][4]);
                }
            }
        }
        __builtin_amdgcn_s_setprio(0);
        // ---- vf load for kb+1 (vf dead after PV; full next-QK-phase cover) ----
        if (kb < kbmax) {
#pragma unroll
            for (int n = 0; n < 4; n++)
#pragma unroll
                for (int kc = 0; kc < 2; kc++)
                    vf[n * 2 + kc] = *(const s16x8*)(vb + (size_t)(n * 16 + lr) * SEQ +
                                                     (kb + 1) * 64 + kc * 32 + quad * 8);
        }
    }

#pragma unroll
    for (int t = 0; t < 4; t++)
#pragma unroll
        for (int r = 0; r < 4; r++) {
            float l = __shfl(oacc[t][4][r], lane & 48);
            float li = 1.0f / l;
#pragma unroll
            for (int n = 0; n < 4; n++)
                o[(size_t)(b * SEQ + q0[t] + quad * 4 + r) * DM + h * 64 + n * 16 + lr] =
                    f2bf(oacc[t][n][r] * li);
        }
}

// ---------------------------------------------------------------------------
extern "C" void kernel_launch(void* const* d_in, const int* in_sizes, int n_in,
                              void* d_out, int out_size, void* d_ws, size_t ws_size,
                              hipStream_t stream) {
    const float* x  = (const float*)d_in[0];
    const float* wq = (const float*)d_in[1];
    const float* wk = (const float*)d_in[2];
    const float* wv = (const float*)d_in[3];
    const float* wo = (const float*)d_in[4];
    float* out = (float*)d_out;

    char* ws = (char*)d_ws;
    const size_t MB = 1024 * 1024;
    us* xb     = (us*)(ws + 0 * MB);    // 16 MiB; reused as abuf (flash out)
    us* abuf   = (us*)(ws + 0 * MB);
    us* wqkvb  = (us*)(ws + 16 * MB);   // 12 MiB (wq|wk|wv) — contiguous with wob
    us* wob    = (us*)(ws + 28 * MB);   // 8 MiB
    us* qkvbuf = (us*)(ws + 36 * MB);   // 24 MiB (4096 x 3072; V cols unused now)
    us* vtbuf  = (us*)(ws + 60 * MB);   // 4 MiB (written by gemm1 epilogue)

    dim3 blk(256);
    cvt_all<<<dim3(9216), blk, 0, stream>>>(x, wq, wk, wv, wo, xb, wqkvb);

    gemm_bt2<us, true><<<dim3(16, 12), dim3(512), 0, stream>>>(xb, wqkvb, qkvbuf, vtbuf,
                                                               4096, 3072, 2048);
    flash_attn<<<dim3(8, 64), blk, 0, stream>>>(qkvbuf, vtbuf, abuf);
    gemm_bt2n<float><<<dim3(16, 16), dim3(512), 0, stream>>>(abuf, wob, out, 4096, 2048, 2048);
}

// Round 15
// 329.181 us; speedup vs baseline: 1.1073x; 1.0322x over previous
//
#include <hip/hip_runtime.h>

#define SEQ    2048
#define DM     2048
#define QKVN   3072
#define VTR    64

typedef short s16x8 __attribute__((ext_vector_type(8)));
typedef float f32x4 __attribute__((ext_vector_type(4)));
typedef float f32x16 __attribute__((ext_vector_type(16)));
typedef unsigned u32x4 __attribute__((ext_vector_type(4)));
typedef unsigned short us;

#define MFMA(a,b,c)   __builtin_amdgcn_mfma_f32_16x16x32_bf16((a),(b),(c),0,0,0)
#define MFMA32(a,b,c) __builtin_amdgcn_mfma_f32_32x32x16_bf16((a),(b),(c),0,0,0)

__device__ __forceinline__ float bf2f(us u) {
    unsigned v = ((unsigned)u) << 16;
    return __builtin_bit_cast(float, v);
}
__device__ __forceinline__ us f2bf(float f) {
    unsigned u = __builtin_bit_cast(unsigned, f);
    u += 0x7FFFu + ((u >> 16) & 1u);
    return (us)(u >> 16);
}
// pack two f32 -> bf16x2 in one instr (T12; no builtin on gfx950)
__device__ __forceinline__ unsigned cvtpk(float lo, float hi) {
    unsigned r;
    asm("v_cvt_pk_bf16_f32 %0, %1, %2" : "=v"(r) : "v"(lo), "v"(hi));
    return r;
}
__device__ __forceinline__ void glds16(const us* g, us* l) {
    __builtin_amdgcn_global_load_lds((__attribute__((address_space(1))) void*)g,
                                     (__attribute__((address_space(3))) void*)l, 16, 0, 0);
}

// ---------------------------------------------------------------------------
// Fused input/weight bf16 conversion (R19-validated): 2 float4/thread -> one
// 16B packed store. All region sizes even in float4 units. Grid 9216 x 256.
// ---------------------------------------------------------------------------
__global__ __launch_bounds__(256) void cvt_all(const float* __restrict__ x,
                                               const float* __restrict__ wq,
                                               const float* __restrict__ wk,
                                               const float* __restrict__ wv,
                                               const float* __restrict__ wo,
                                               us* __restrict__ xb,
                                               us* __restrict__ wdst) {
    int i = (blockIdx.x * blockDim.x + threadIdx.x) * 2;   // float4 idx, 4718592 total
    const float* src;
    int off;
    if (i < 2097152)      { src = x;  off = 0; }
    else {
        int j = i - 2097152;
        if (j < 1048576)      { src = wq; off = 2097152; }
        else if (j < 1310720) { src = wk; off = 2097152 + 1048576; }
        else if (j < 1572864) { src = wv; off = 2097152 + 1310720; }
        else                  { src = wo; off = 2097152 + 1572864; }
    }
    const int base = i - off;
    float4 v0 = ((const float4*)src)[base];
    float4 v1 = ((const float4*)src)[base + 1];
    s16x8 o;
    o[0] = (short)f2bf(v0.x); o[1] = (short)f2bf(v0.y);
    o[2] = (short)f2bf(v0.z); o[3] = (short)f2bf(v0.w);
    o[4] = (short)f2bf(v1.x); o[5] = (short)f2bf(v1.y);
    o[6] = (short)f2bf(v1.z); o[7] = (short)f2bf(v1.w);
    us* d = (i < 2097152) ? xb : wdst;
    const int di = (i < 2097152) ? i : i - 2097152;
    *(s16x8*)(d + di * 4) = o;                // 16B aligned (di even)
}

// ---------------------------------------------------------------------------
// R16/R18-validated GEMM (gemm1): 256x256 tile, BK=64, 512 threads, 4
// phases/K-tile, counted vmcnt, raw s_barrier, both-sides swizzle, setprio.
// V columns (n0>=2560) write TRANSPOSED directly to vt (absorbs
// transpose_v). ROPE inline trig. Grid (16,12)=192 blocks.
// ---------------------------------------------------------------------------
template <typename OutT, bool ROPE>
__global__ __launch_bounds__(512) void gemm_bt2(const us* __restrict__ A, const us* __restrict__ W,
                                                OutT* __restrict__ C, us* __restrict__ vt,
                                                int M, int N, int K) {
    __shared__ us lA[2][2][128 * 64];         // [parity][half][row*64+col]  64 KiB
    __shared__ us lB[2][2][128 * 64];         // 64 KiB
    const int tid = threadIdx.x, lane = tid & 63, wave = tid >> 6;
    const int quad = lane >> 4, lr = lane & 15;
    const int mh = wave >> 2;                 // wave's A half (128-row group)
    const int wnx = wave & 3;                 // wave's 64-col group
    const int bh = wnx >> 1, br0 = (wnx & 1) * 64;
    const int m0 = blockIdx.x * 256, n0 = blockIdx.y * 256;

    const int srow = tid >> 3;
    const int scol = ((tid & 7) ^ (srow & 7)) * 8;   // pre-swizzled global col (elems)
    const int sdst = srow * 64 + (tid & 7) * 8;      // linear LDS dest (elems)

    const us* gA = A + (size_t)m0 * K;
    const us* gB = W + (size_t)n0 * K;

    auto stageH = [&](int s) {
        const int t = s >> 2, ty = s & 3, par = t & 1;
        const us* src;
        us* dst;
        if (ty < 2) { src = gA + (size_t)(ty * 128) * K;       dst = &lA[par][ty][0]; }
        else        { src = gB + (size_t)((ty - 2) * 128) * K; dst = &lB[par][ty - 2][0]; }
        src += t * 64;
        glds16(src + (size_t)srow * K + scol,        dst + sdst);
        glds16(src + (size_t)(srow + 64) * K + scol, dst + sdst + 64 * 64);
    };

    const int rsw = (lr & 7) << 3;            // read-side swizzle (elems); row&7 == lr&7
    auto rdA = [&](int par, int kk, int i) {
        return *(const s16x8*)&lA[par][mh][(i * 16 + lr) * 64 + ((kk * 32 + quad * 8) ^ rsw)];
    };
    auto rdB = [&](int par, int kk, int j) {
        return *(const s16x8*)&lB[par][bh][(br0 + j * 16 + lr) * 64 + ((kk * 32 + quad * 8) ^ rsw)];
    };

    f32x4 acc[8][4] = {};
    const int NT = K / 64;

    stageH(0); stageH(1); stageH(2); stageH(3); stageH(4);
    asm volatile("s_waitcnt vmcnt(2)" ::: "memory");
    __builtin_amdgcn_s_barrier();

    s16x8 af[2][4], ag[2][4], bfr[2][2], bg[2][2];
    for (int t = 0; t < NT; ++t) {
        const int par = t & 1;
        // ---- phase 0: (i 0-3) x (j 0-1) ----
#pragma unroll
        for (int kk = 0; kk < 2; kk++) {
#pragma unroll
            for (int i = 0; i < 4; i++) af[kk][i] = rdA(par, kk, i);
#pragma unroll
            for (int j = 0; j < 2; j++) bfr[kk][j] = rdB(par, kk, j);
        }
        if (t + 1 < NT) stageH(4 * (t + 1) + 1);
        __builtin_amdgcn_s_barrier();
        asm volatile("s_waitcnt lgkmcnt(0)" ::: "memory");
        __builtin_amdgcn_s_setprio(1);
#pragma unroll
        for (int i = 0; i < 4; i++)
#pragma unroll
            for (int j = 0; j < 2; j++)
#pragma unroll
                for (int kk = 0; kk < 2; kk++)
                    acc[i][j] = MFMA(af[kk][i], bfr[kk][j], acc[i][j]);
        __builtin_amdgcn_s_setprio(0);
        __builtin_amdgcn_s_barrier();
        // ---- phase 1: (i 0-3) x (j 2-3) ----
#pragma unroll
        for (int kk = 0; kk < 2; kk++)
#pragma unroll
            for (int j = 0; j < 2; j++) bg[kk][j] = rdB(par, kk, 2 + j);
        if (t + 1 < NT) stageH(4 * (t + 1) + 2);
        __builtin_amdgcn_s_barrier();
        asm volatile("s_waitcnt lgkmcnt(0)" ::: "memory");
        __builtin_amdgcn_s_setprio(1);
#pragma unroll
        for (int i = 0; i < 4; i++)
#pragma unroll
            for (int j = 0; j < 2; j++)
#pragma unroll
                for (int kk = 0; kk < 2; kk++)
                    acc[i][2 + j] = MFMA(af[kk][i], bg[kk][j], acc[i][2 + j]);
        __builtin_amdgcn_s_setprio(0);
        __builtin_amdgcn_s_barrier();
        // ---- phase 2: (i 4-7) x (j 0-1) ----
#pragma unroll
        for (int kk = 0; kk < 2; kk++)
#pragma unroll
            for (int i = 0; i < 4; i++) ag[kk][i] = rdA(par, kk, 4 + i);
        if (t + 1 < NT) stageH(4 * (t + 1) + 3);
        __builtin_amdgcn_s_barrier();
        asm volatile("s_waitcnt lgkmcnt(0)" ::: "memory");
        __builtin_amdgcn_s_setprio(1);
#pragma unroll
        for (int i = 0; i < 4; i++)
#pragma unroll
            for (int j = 0; j < 2; j++)
#pragma unroll
                for (int kk = 0; kk < 2; kk++)
                    acc[4 + i][j] = MFMA(ag[kk][i], bfr[kk][j], acc[4 + i][j]);
        __builtin_amdgcn_s_setprio(0);
        __builtin_amdgcn_s_barrier();
        // ---- phase 3: (i 4-7) x (j 2-3); stage t+2's H0 (parity par, safe) ----
        if (t + 2 < NT) stageH(4 * (t + 2));
        __builtin_amdgcn_s_setprio(1);
#pragma unroll
        for (int i = 0; i < 4; i++)
#pragma unroll
            for (int j = 0; j < 2; j++)
#pragma unroll
                for (int kk = 0; kk < 2; kk++)
                    acc[4 + i][2 + j] = MFMA(ag[kk][i], bg[kk][j], acc[4 + i][2 + j]);
        __builtin_amdgcn_s_setprio(0);
        if (t + 1 < NT) {
            if (t + 2 < NT) asm volatile("s_waitcnt vmcnt(2)" ::: "memory");
            else            asm volatile("s_waitcnt vmcnt(0)" ::: "memory");
            __builtin_amdgcn_s_barrier();
        }
    }

    const bool vblk = ROPE && (n0 >= 2560);   // V block: write transposed to vt
#pragma unroll
    for (int i = 0; i < 8; i++)
#pragma unroll
        for (int j = 0; j < 4; j++) {
            const int row0 = m0 + mh * 128 + i * 16 + quad * 4;
            const int col  = n0 + wnx * 64 + j * 16 + lr;
            if (vblk) {
                const int d = col - 2560;                 // kvh*64 + dd
                const int b = row0 >> 11, s = row0 & (SEQ - 1);
                ushort4 o4;
                o4.x = f2bf(acc[i][j][0]); o4.y = f2bf(acc[i][j][1]);
                o4.z = f2bf(acc[i][j][2]); o4.w = f2bf(acc[i][j][3]);
                *(ushort4*)(vt + ((size_t)b * 512 + d) * SEQ + s) = o4;
            } else {
#pragma unroll
                for (int r = 0; r < 4; r++) {
                    const int row = row0 + r;
                    float v = acc[i][j][r];
                    if (ROPE && n0 < 2560) {
                        int pair = (col >> 1) & 31;
                        float inv = exp2f((float)pair * (-13.2877124f / 32.0f));
                        float ang = (float)(row & (SEQ - 1)) * inv;
                        float c = __cosf(ang), sn = __sinf(ang);
                        float p = __shfl_xor(v, 1);
                        v = v * c + ((col & 1) ? p * sn : -p * sn);
                    }
                    if constexpr (sizeof(OutT) == 2)
                        C[(size_t)row * N + col] = f2bf(v);
                    else
                        C[(size_t)row * N + col] = v;
                }
            }
        }
}

// ---------------------------------------------------------------------------
// R16-validated GEMM (gemm2): 256x128 tile, BK=64, 512 threads, 2 phases/
// K-tile, counted vmcnt, raw s_barrier, both-sides swizzle, setprio.
// Grid (16,16) = 256 blocks = 100% CU fill.
// ---------------------------------------------------------------------------
template <typename OutT>
__global__ __launch_bounds__(512) void gemm_bt2n(const us* __restrict__ A, const us* __restrict__ W,
                                                 OutT* __restrict__ C, int M, int N, int K) {
    __shared__ us lA[2][2][128 * 64];         // 64 KiB
    __shared__ us lB[2][128 * 64];            // 32 KiB
    const int tid = threadIdx.x, lane = tid & 63, wave = tid >> 6;
    const int quad = lane >> 4, lr = lane & 15;
    const int mh = wave >> 2;                 // wave's A half (128-row group)
    const int wnx = wave & 3;                 // wave's 32-col group
    const int m0 = blockIdx.x * 256, n0 = blockIdx.y * 128;

    const int srow = tid >> 3;
    const int scol = ((tid & 7) ^ (srow & 7)) * 8;
    const int sdst = srow * 64 + (tid & 7) * 8;

    const us* gA = A + (size_t)m0 * K;
    const us* gB = W + (size_t)n0 * K;

    // ty: 0=A0, 1=A1, 2=B
    auto stageH = [&](int t, int ty) {
        const int par = t & 1;
        const us* src;
        us* dst;
        if (ty < 2) { src = gA + (size_t)(ty * 128) * K; dst = &lA[par][ty][0]; }
        else        { src = gB;                           dst = &lB[par][0]; }
        src += t * 64;
        glds16(src + (size_t)srow * K + scol,        dst + sdst);
        glds16(src + (size_t)(srow + 64) * K + scol, dst + sdst + 64 * 64);
    };

    const int rsw = (lr & 7) << 3;
    auto rdA = [&](int par, int kk, int i) {
        return *(const s16x8*)&lA[par][mh][(i * 16 + lr) * 64 + ((kk * 32 + quad * 8) ^ rsw)];
    };
    auto rdB = [&](int par, int kk, int j) {
        return *(const s16x8*)&lB[par][(wnx * 32 + j * 16 + lr) * 64 + ((kk * 32 + quad * 8) ^ rsw)];
    };

    f32x4 acc[8][2] = {};
    const int NT = K / 64;

    stageH(0, 0); stageH(0, 1); stageH(0, 2); stageH(1, 0);
    asm volatile("s_waitcnt vmcnt(2)" ::: "memory");
    __builtin_amdgcn_s_barrier();

    s16x8 af[2][4], ag[2][4], bfr[2][2];
    for (int t = 0; t < NT; ++t) {
        const int par = t & 1;
        // ---- phase 0: (i 0-3) x (j 0-1) ----
#pragma unroll
        for (int kk = 0; kk < 2; kk++) {
#pragma unroll
            for (int i = 0; i < 4; i++) af[kk][i] = rdA(par, kk, i);
#pragma unroll
            for (int j = 0; j < 2; j++) bfr[kk][j] = rdB(par, kk, j);
        }
        if (t + 1 < NT) stageH(t + 1, 1);
        __builtin_amdgcn_s_barrier();
        asm volatile("s_waitcnt lgkmcnt(0)" ::: "memory");
        __builtin_amdgcn_s_setprio(1);
#pragma unroll
        for (int i = 0; i < 4; i++)
#pragma unroll
            for (int j = 0; j < 2; j++)
#pragma unroll
                for (int kk = 0; kk < 2; kk++)
                    acc[i][j] = MFMA(af[kk][i], bfr[kk][j], acc[i][j]);
        __builtin_amdgcn_s_setprio(0);
        __builtin_amdgcn_s_barrier();
        // ---- phase 1: (i 4-7) x (j 0-1); then stage t+2.A0 (parity par, safe) ----
#pragma unroll
        for (int kk = 0; kk < 2; kk++)
#pragma unroll
            for (int i = 0; i < 4; i++) ag[kk][i] = rdA(par, kk, 4 + i);
        if (t + 1 < NT) stageH(t + 1, 2);
        __builtin_amdgcn_s_barrier();
        asm volatile("s_waitcnt lgkmcnt(0)" ::: "memory");
        __builtin_amdgcn_s_setprio(1);
#pragma unroll
        for (int i = 0; i < 4; i++)
#pragma unroll
            for (int j = 0; j < 2; j++)
#pragma unroll
                for (int kk = 0; kk < 2; kk++)
                    acc[4 + i][j] = MFMA(ag[kk][i], bfr[kk][j], acc[4 + i][j]);
        __builtin_amdgcn_s_setprio(0);
        if (t + 2 < NT) stageH(t + 2, 0);
        if (t + 1 < NT) {
            if (t + 2 < NT) asm volatile("s_waitcnt vmcnt(2)" ::: "memory");
            else            asm volatile("s_waitcnt vmcnt(0)" ::: "memory");
            __builtin_amdgcn_s_barrier();
        }
    }

#pragma unroll
    for (int i = 0; i < 8; i++)
#pragma unroll
        for (int j = 0; j < 2; j++)
#pragma unroll
            for (int r = 0; r < 4; r++) {
                int row = m0 + mh * 128 + i * 16 + quad * 4 + r;
                int col = n0 + wnx * 32 + j * 16 + lr;
                if constexpr (sizeof(OutT) == 2)
                    C[(size_t)row * N + col] = f2bf(acc[i][j][r]);
                else
                    C[(size_t)row * N + col] = acc[i][j][r];
            }
}

// ---------------------------------------------------------------------------
// R20 flash: swapped-QK 32x32 MFMA, softmax fully in-register, ZERO LDS.
// QK computes S^T = mfma32(K, Q): C col=lane&31=q, row-reg -> key =
// (r&3)+8*(r>>2)+4*half (m74/m101-verified layout). Each lane holds 16
// P-values of its own q-row -> exp2 + row-sum lane-local (l via adds, no
// ones-MFMA). P->bf16 via v_cvt_pk_bf16_f32 pairs; __shfl_xor(,32) swaps
// the partner half's keys; half-select assembles PV A-frags (32x32x16
// k-split: lanes<32 k0-7, >=32 k8-15). V feeds B-frags straight from vt
// (d-major -> contiguous keys). The old 64 ds_write + lgkmcnt(0) drain +
// ds_read round-trip is GONE. Wave owns q-tile pair {j, 63-j} (uniform 65
// tile-iters); kf/vf prefetch slots mirror the proven R6 schedule.
// Grid (8, B*H) = 512 blocks; ~225 regs -> 2 waves/SIMD.
// ---------------------------------------------------------------------------
__global__ __launch_bounds__(256, 2) void flash_attn(const us* __restrict__ qkv,
                                                     const us* __restrict__ vt,
                                                     us* __restrict__ o) {
    const int bh = blockIdx.y, b = bh >> 5, h = bh & 31, kvh = h >> 2;
    const int wave = threadIdx.x >> 6, lane = threadIdx.x & 63;
    const int half = lane >> 5, l5 = lane & 31;
    const int jb = ((int)blockIdx.x + (int)(blockIdx.y >> 3)) & 7;
    const int j = jb * 4 + wave;              // 0..31
    const int q00 = j * 32, q01 = (63 - j) * 32;
    const int kbm0 = j, kbm1 = 63 - j;
    const us* kbase = qkv + (size_t)b * SEQ * QKVN + 2048 + kvh * 64;
    const us* vb = vt + (size_t)(b * 8 + kvh) * VTR * SEQ;
    const float QS = 0.125f * 1.44269504f;    // scale * log2(e)

    // Q fragments (B-operand: lane holds Q[q=l5][d = dc*16 + half*8 + 0..7]), scaled
    s16x8 qf[2][4];
#pragma unroll
    for (int t = 0; t < 2; t++) {
        const int q0t = t ? q01 : q00;
        const us* qb = qkv + (size_t)(b * SEQ + q0t + l5) * QKVN + h * 64 + half * 8;
#pragma unroll
        for (int dc = 0; dc < 4; dc++) {
            qf[t][dc] = *(const s16x8*)(qb + dc * 16);
#pragma unroll
            for (int e = 0; e < 8; e++)
                qf[t][dc][e] = (short)f2bf(bf2f((us)qf[t][dc][e]) * QS);
        }
    }

    f32x16 oacc[2][2] = {};                   // [tile][d-half], C: q=reg-row, d=dh*32+l5
    float lsum0 = 0.f, lsum1 = 0.f;

    s16x8 kf[4], vf[4];
    auto load_k = [&](int kb) {               // A-operand: K[key=l5][d=dc*16+half*8+j]
        const us* kp = kbase + (size_t)(kb * 32 + l5) * QKVN + half * 8;
#pragma unroll
        for (int dc = 0; dc < 4; dc++) kf[dc] = *(const s16x8*)(kp + dc * 16);
    };
    auto load_v = [&](int kb) {               // B-operand: V[k=kc*16+half*8+j][d=dh*32+l5]
#pragma unroll
        for (int kc = 0; kc < 2; kc++)
#pragma unroll
            for (int dh = 0; dh < 2; dh++)
                vf[kc * 2 + dh] = *(const s16x8*)(vb + (size_t)(dh * 32 + l5) * SEQ +
                                                  kb * 32 + kc * 16 + half * 8);
    };
    load_k(0);
    load_v(0);

    // exp2 + pack + PV for one tile (all refs named: no runtime-indexed arrays)
    auto tilepv = [&](int kb, int kbt, int q0t, f32x16& sc, float& ls,
                      f32x16& od0, f32x16& od1) {
        float p[16];
        if (kb == kbt) {                      // diagonal: causal mask
#pragma unroll
            for (int r = 0; r < 16; r++) {
                int key = kb * 32 + (r & 3) + 8 * (r >> 2) + 4 * half;
                float s = (key > q0t + l5) ? -1e30f : sc[r];
                p[r] = exp2f(s);
                ls += p[r];
            }
        } else {
#pragma unroll
            for (int r = 0; r < 16; r++) { p[r] = exp2f(sc[r]); ls += p[r]; }
        }
        unsigned pr[8], sw[8];
#pragma unroll
        for (int i = 0; i < 8; i++) pr[i] = cvtpk(p[2 * i], p[2 * i + 1]);
#pragma unroll
        for (int i = 0; i < 8; i++) sw[i] = __shfl_xor(pr[i], 32);
        u32x4 w0, w1;                         // A-frags: k = kc*16 + half*8 + 0..7
        w0[0] = half ? sw[2] : pr[0]; w0[1] = half ? sw[3] : pr[1];
        w0[2] = half ? pr[2] : sw[0]; w0[3] = half ? pr[3] : sw[1];
        w1[0] = half ? sw[6] : pr[4]; w1[1] = half ? sw[7] : pr[5];
        w1[2] = half ? pr[6] : sw[4]; w1[3] = half ? pr[7] : sw[5];
        s16x8 fa0 = __builtin_bit_cast(s16x8, w0);
        s16x8 fa1 = __builtin_bit_cast(s16x8, w1);
        od0 = MFMA32(fa0, vf[0], od0);        // kc=0, dh=0
        od0 = MFMA32(fa1, vf[2], od0);        // kc=1, dh=0
        od1 = MFMA32(fa0, vf[1], od1);        // kc=0, dh=1
        od1 = MFMA32(fa1, vf[3], od1);        // kc=1, dh=1
    };

    for (int kb = 0; kb <= kbm1; kb++) {
        const bool a0 = (kb <= kbm0);
        f32x16 s0 = {}, s1 = {};
        if (a0) {
#pragma unroll
            for (int dc = 0; dc < 4; dc++) s0 = MFMA32(kf[dc], qf[0][dc], s0);
        }
#pragma unroll
        for (int dc = 0; dc < 4; dc++) s1 = MFMA32(kf[dc], qf[1][dc], s1);
        // kf prefetch for kb+1 (kf dead until next iteration)
        if (kb < kbm1) load_k(kb + 1);
        if (a0) tilepv(kb, kbm0, q00, s0, lsum0, oacc[0][0], oacc[0][1]);
        tilepv(kb, kbm1, q01, s1, lsum1, oacc[1][0], oacc[1][1]);
        // vf prefetch for kb+1 (vf dead after PV)
        if (kb < kbm1) load_v(kb + 1);
    }

    // epilogue: full row-sum via partner add; broadcast l[q] via shfl
#pragma unroll
    for (int t = 0; t < 2; t++) {
        const float lsel = t ? lsum1 : lsum0;
        const int q0t = t ? q01 : q00;
        const float lf = lsel + __shfl_xor(lsel, 32);
#pragma unroll
        for (int r = 0; r < 16; r++) {
            const int qrow = (r & 3) + 8 * (r >> 2) + 4 * half;
            const float li = 1.0f / __shfl(lf, qrow);
#pragma unroll
            for (int dh = 0; dh < 2; dh++) {
                const float v = (t ? oacc[1][dh][r] : oacc[0][dh][r]) * li;
                o[(size_t)(b * SEQ + q0t + qrow) * DM + h * 64 + dh * 32 + l5] = f2bf(v);
            }
        }
    }
}

// ---------------------------------------------------------------------------
extern "C" void kernel_launch(void* const* d_in, const int* in_sizes, int n_in,
                              void* d_out, int out_size, void* d_ws, size_t ws_size,
                              hipStream_t stream) {
    const float* x  = (const float*)d_in[0];
    const float* wq = (const float*)d_in[1];
    const float* wk = (const float*)d_in[2];
    const float* wv = (const float*)d_in[3];
    const float* wo = (const float*)d_in[4];
    float* out = (float*)d_out;

    char* ws = (char*)d_ws;
    const size_t MB = 1024 * 1024;
    us* xb     = (us*)(ws + 0 * MB);    // 16 MiB; reused as abuf (flash out)
    us* abuf   = (us*)(ws + 0 * MB);
    us* wqkvb  = (us*)(ws + 16 * MB);   // 12 MiB (wq|wk|wv) — contiguous with wob
    us* wob    = (us*)(ws + 28 * MB);   // 8 MiB
    us* qkvbuf = (us*)(ws + 36 * MB);   // 24 MiB (4096 x 3072; V cols unused)
    us* vtbuf  = (us*)(ws + 60 * MB);   // 4 MiB (written by gemm1 epilogue)

    dim3 blk(256);
    cvt_all<<<dim3(9216), blk, 0, stream>>>(x, wq, wk, wv, wo, xb, wqkvb);

    gemm_bt2<us, true><<<dim3(16, 12), dim3(512), 0, stream>>>(xb, wqkvb, qkvbuf, vtbuf,
                                                               4096, 3072, 2048);
    flash_attn<<<dim3(8, 64), blk, 0, stream>>>(qkvbuf, vtbuf, abuf);
    gemm_bt2n<float><<<dim3(16, 16), dim3(512), 0, stream>>>(abuf, wob, out, 4096, 2048, 2048);
}